// Round 1
// baseline (31768.661 us; speedup 1.0000x reference)
//
#include <hip/hip_runtime.h>
#include <math.h>

// ---------------- problem constants ----------------
constexpr int U  = 160;
constexpr int LN = 512;
constexpr int NN = 400;
constexpr int S  = 16;
constexpr int W_ = 64;
constexpr float C_VIOL = 2.0e4f;
constexpr int N_ITERS = 500;
constexpr int N_POWER = 30;   // reference does 30 normalized iters + 1 extra for Lop

// solver launch shape
#define WGN 32
#define TPB 256
#define NTH (WGN*TPB)
#define NWAVE (WGN*4)

// ---------------- ws layout (floats) ----------------
constexpr int O_HG    = 0;                 // Hg[LN][U]
constexpr int O_HGT   = O_HG   + LN*U;     // HgT[U][LN]
constexpr int O_PTDFT = O_HGT  + U*LN;     // PTDFT[NN][LN]
constexpr int O_HW    = O_PTDFT+ NN*LN;    // Hw[LN][W]
constexpr int O_PDL   = O_HW   + LN*W_;    // node_L@Pd [NN]
constexpr int O_CF    = O_PDL  + NN;       // const_flow [LN]
constexpr int O_B3    = O_CF   + LN;       // Cap-cf
constexpr int O_B4    = O_B3   + LN;       // Cap+cf
constexpr int O_BWS   = O_B4   + LN;       // b_ws[LN][S]
constexpr int O_BE1   = O_BWS  + LN*S;
constexpr int O_BE2   = O_BE1  + 1;        // [S]
constexpr int O_MUT   = O_BE2  + S;        // ---- mutable region starts ----
// x (also used as power-iteration v)
constexpr int O_XP   = O_MUT;
constexpr int O_XRU  = O_XP  + U;
constexpr int O_XRD  = O_XRU + U;
constexpr int O_XPU  = O_XRD + U;          // [U][S]
constexpr int O_XPD  = O_XPU + U*S;
constexpr int O_XSU  = O_XPD + U*S;        // [NN]
constexpr int O_XSD  = O_XSU + NN;
constexpr int O_XEND = O_XSD + NN;
// xb
constexpr int O_BP   = O_XEND;
constexpr int O_BRU  = O_BP  + U;
constexpr int O_BRD  = O_BRU + U;
constexpr int O_BPU  = O_BRD + U;
constexpr int O_BPD  = O_BPU + U*S;
constexpr int O_BSU  = O_BPD + U*S;
constexpr int O_BSD  = O_BSU + NN;
constexpr int O_DIFF = O_BSD + NN;         // xb_pu-xb_pd [U][S]
constexpr int O_SDIFF= O_DIFF+ U*S;        // xb_su-xb_sd [NN]
// y
constexpr int O_Y1 = O_SDIFF + NN;         // [U]
constexpr int O_Y2 = O_Y1 + U;
constexpr int O_Y3 = O_Y2 + U;             // [LN]
constexpr int O_Y4 = O_Y3 + LN;
constexpr int O_Y5 = O_Y4 + LN;            // [U][S]
constexpr int O_Y6 = O_Y5 + U*S;
constexpr int O_Y7 = O_Y6 + U*S;           // [LN][S]
constexpr int O_Y8 = O_Y7 + LN*S;
constexpr int O_Z1 = O_Y8 + LN*S;
constexpr int O_Z2 = O_Z1 + 1;             // [S]
constexpr int O_ZS = O_Z2 + S;             // sum(z2)
// pdhg eq-sum parity buffers
constexpr int O_PAE1 = O_ZS + 1;           // [2]
constexpr int O_PAE2 = O_PAE1 + 2;         // [2][16]
constexpr int O_PSUSD= O_PAE2 + 32;        // [2]
// shared scratch between phases
constexpr int O_S78T = O_PSUSD + 2;        // s78 transposed [S][LN]
constexpr int O_S78S = O_S78T + S*LN;      // [LN]
constexpr int O_W34  = O_S78S + LN;        // y3-y4+s78s [LN]
constexpr int O_ZEND = O_W34  + LN;        // ---- phase-Z zero region end ----
// power-iteration accumulators (slot per iteration, zeroed at setup only)
constexpr int O_N2  = O_ZEND;              // [32]
constexpr int O_EQ1 = O_N2  + 32;          // [32]
constexpr int O_EQ2 = O_EQ1 + 32;          // [32][16]
constexpr int O_EQS = O_EQ2 + 32*16;       // [32]
constexpr int O_BAR = O_EQS + 32;          // barrier counter (as unsigned)
constexpr int WSF   = O_BAR + 1;

// ---------------- device helpers ----------------
__device__ __forceinline__ float wred64(float v){
#pragma unroll
  for (int o = 32; o > 0; o >>= 1) v += __shfl_xor(v, o, 64);
  return v;
}
__device__ __forceinline__ float red16(float v){   // sum within groups of 16 lanes
  v += __shfl_xor(v, 1, 64); v += __shfl_xor(v, 2, 64);
  v += __shfl_xor(v, 4, 64); v += __shfl_xor(v, 8, 64);
  return v;
}
__device__ __forceinline__ float redchunk(float v){ // sum over the 4 chunk-groups
  v += __shfl_xor(v, 16, 64); v += __shfl_xor(v, 32, 64);
  return v;
}

// ---------------- setup kernels ----------------
__global__ void k_zero(float* ws){
  int gt = blockIdx.x*blockDim.x + threadIdx.x;
  int nt = gridDim.x*blockDim.x;
  for (int i = gt; i < WSF - O_MUT; i += nt){
    int a = O_MUT + i;
    float v = 0.f;
    if (a >= O_XP && a < O_XEND) v = 1.f;          // power-iteration v0 = ones
    if (a == O_EQ1) v = (float)U;                  // eq1 of ones = sum(p)=U
    ws[a] = v;
  }
}

__global__ void k_pdl(const float* nL, const float* Pd, float* ws){
  int n = blockIdx.x; int lane = threadIdx.x;
  float p = 0.f;
  for (int m = lane; m < NN; m += 64) p += nL[n*NN+m]*Pd[m];
  p = wred64(p);
  if (lane == 0) ws[O_PDL+n] = p;
}

__global__ void k_hg(const float* PTDF, const float* nG, float* ws){
  int l = blockIdx.x, u = threadIdx.x;
  float acc = 0.f;
  for (int n = 0; n < NN; ++n) acc += PTDF[l*NN+n]*nG[n*U+u];
  ws[O_HG + l*U + u]  = acc;
  ws[O_HGT + u*LN + l] = acc;
}

__global__ void k_hw(const float* PTDF, const float* nW, float* ws){
  int l = blockIdx.x, w = threadIdx.x;
  float acc = 0.f;
  for (int n = 0; n < NN; ++n) acc += PTDF[l*NN+n]*nW[n*W_+w];
  ws[O_HW + l*W_ + w] = acc;
}

__global__ void k_tp(const float* PTDF, float* ws){
  int n = blockIdx.x;
  for (int l = threadIdx.x; l < LN; l += blockDim.x)
    ws[O_PTDFT + n*LN + l] = PTDF[l*NN + n];
}

__global__ void k_misc(const float* PTDF, const float* w_exp, const float* w_scen,
                       const float* Cap, float* ws){
  int l = blockIdx.x; int lane = threadIdx.x;
  float part = ws[O_HW + l*W_ + lane]*w_exp[lane];
  for (int n = lane; n < NN; n += 64) part -= PTDF[l*NN+n]*ws[O_PDL+n];
  float cfv = wred64(part);
  if (lane == 0){
    ws[O_CF+l] = cfv;
    ws[O_B3+l] = Cap[l] - cfv;
    ws[O_B4+l] = Cap[l] + cfv;
  }
  int s = lane & 15, ch = lane >> 4;
  float bp = 0.f;
  for (int w = ch*16; w < ch*16+16; ++w) bp += ws[O_HW + l*W_ + w]*w_scen[s*W_+w];
  bp = redchunk(bp);
  if (lane < 16) ws[O_BWS + l*S + s] = bp;
}

__global__ void k_scal(const float* Pd, const float* w_exp, const float* w_scen, float* ws){
  __shared__ float sr[256];
  int tid = threadIdx.x;
  float p = 0.f;
  for (int i = tid; i < NN; i += 256) p += Pd[i];
  for (int i = tid; i < W_; i += 256) p -= w_exp[i];
  sr[tid] = p; __syncthreads();
  for (int o = 128; o > 0; o >>= 1){ if (tid < o) sr[tid] += sr[tid+o]; __syncthreads(); }
  if (tid == 0) ws[O_BE1] = sr[0];
  if (tid < S){
    float a = 0.f;
    for (int w = 0; w < W_; ++w) a += w_scen[tid*W_+w];
    ws[O_BE2+tid] = -a;
  }
}

// ---------------- persistent solver ----------------
extern "C" __global__ void __launch_bounds__(TPB)
k_solver(float* __restrict__ ws, const float* __restrict__ Pmax,
         const float* __restrict__ Cost, const float* __restrict__ Crup,
         const float* __restrict__ Crdn, const float* __restrict__ PTDF,
         const float* __restrict__ Cap, float* __restrict__ out)
{
  const int tid  = threadIdx.x;
  const int lane = tid & 63;
  const int wv   = tid >> 6;
  const int gw   = blockIdx.x*4 + wv;
  const int gtid = blockIdx.x*TPB + tid;
  unsigned* bar = (unsigned*)(ws + O_BAR);
  unsigned nbar = 0;
  __shared__ float s_acc[20];   // 0..15: per-s eq2; 16: ae1/eq1; 17: susd; 18: n2
  __shared__ float sred[TPB];

  auto gbar = [&](){
    ++nbar;
    __syncthreads();
    if (tid == 0){
      __threadfence();                       // agent release (L2 writeback)
      atomicAdd(bar, 1u);
      while (atomicAdd(bar, 0u) < nbar*(unsigned)WGN)
        __builtin_amdgcn_s_sleep(2);
      __threadfence();                       // agent acquire (cache invalidate)
    }
    __syncthreads();
  };

  // ---- phase Y: PDHG dual update (pd=true) or power A(v) (pd=false) ----
  auto phaseY = [&](bool pd, int k){
    float scl = 1.f, sig = 0.f;
    if (pd) sig = 0.9f / sqrtf(sqrtf(ws[O_N2+31]));
    else if (k > 0) scl = 1.f / sqrtf(ws[O_N2+k]);
    const float* Xp  = ws + (pd ? O_BP  : O_XP);
    const float* Xru = ws + (pd ? O_BRU : O_XRU);
    const float* Xrd = ws + (pd ? O_BRD : O_XRD);
    const float* Xpu = ws + (pd ? O_BPU : O_XPU);
    const float* Xpd = ws + (pd ? O_BPD : O_XPD);

    // (g) eq-dual update, WG0 wave0, PDHG only
    if (pd && blockIdx.x == 0 && wv == 0){
      int p = k & 1, q = 1 - p;
      float zn = 0.f;
      if (lane < 16){
        float ae2 = ws[O_PAE2 + p*16 + lane] + ws[O_PSUSD + p];
        zn = ws[O_Z2+lane] + sig*(ae2 - ws[O_BE2+lane]);
        ws[O_Z2+lane] = zn;
      }
      float zst = red16(zn);
      if (lane == 0){
        ws[O_ZS] = zst;
        ws[O_Z1] = ws[O_Z1] + sig*(ws[O_PAE1+p] - ws[O_BE1]);
      }
      if (lane < 16) ws[O_PAE2 + q*16 + lane] = 0.f;
      if (lane == 16) ws[O_PAE1+q] = 0.f;
      if (lane == 17) ws[O_PSUSD+q] = 0.f;
    }

    // (e) y1/y2 per-u
    if (gtid < U){
      int u = gtid;
      if (pd){
        float xbp = Xp[u];
        ws[O_Y1+u] = fmaxf(ws[O_Y1+u] + sig*(xbp + Xru[u] - Pmax[u]), 0.f);
        ws[O_Y2+u] = fmaxf(ws[O_Y2+u] + sig*(Xrd[u] - xbp), 0.f);
      } else {
        float vp = Xp[u];
        ws[O_Y1+u] = (vp + Xru[u])*scl;
        ws[O_Y2+u] = (Xrd[u] - vp)*scl;
      }
    } else if (gtid < U + U*S){ // (f) y5/y6 per-(u,s)
      int idx = gtid - U; int u = idx >> 4;
      if (pd){
        ws[O_Y5+idx] = fmaxf(ws[O_Y5+idx] + sig*(Xpu[idx] - Xru[u]), 0.f);
        ws[O_Y6+idx] = fmaxf(ws[O_Y6+idx] + sig*(Xpd[idx] - Xrd[u]), 0.f);
      } else {
        ws[O_Y5+idx] = (Xpu[idx] - Xru[u])*scl;
        ws[O_Y6+idx] = (Xpd[idx] - Xrd[u])*scl;
      }
    }

    // (d) per-line: fp, pn, scen, y3/y4/y7/y8, s78T, s78s, w34
    for (int l = gw; l < LN; l += NWAVE){
      const float* Hgr = ws + O_HG + l*U;
      const float* Pr  = PTDF + l*NN;
      float a = 0.f;
      for (int u2 = lane; u2 < U; u2 += 64) a += Hgr[u2]*Xp[u2];
      float b = 0.f;
      for (int n2 = lane; n2 < NN; n2 += 64) b += Pr[n2]*ws[O_SDIFF+n2];
      float fp = wred64(a);
      float pn = wred64(b);
      int s = lane & 15, ch = lane >> 4;
      float sc = 0.f;
      int u0 = ch*40;
      for (int u2 = u0; u2 < u0+40; ++u2) sc += Hgr[u2]*ws[O_DIFF + u2*16 + s];
      sc = redchunk(sc);
      float scen = sc + fp + pn;
      float b3l = ws[O_B3+l], b4l = ws[O_B4+l];
      float sv;
      if (pd){
        float bw  = ws[O_BWS + l*16 + s];
        float y7n = fmaxf(ws[O_Y7 + l*16 + s] + sig*( scen - (b3l - bw)), 0.f);
        float y8n = fmaxf(ws[O_Y8 + l*16 + s] + sig*(-scen - (b4l + bw)), 0.f);
        if (lane < 16){ ws[O_Y7 + l*16 + s] = y7n; ws[O_Y8 + l*16 + s] = y8n; }
        sv = y7n - y8n;
      } else {
        sv = 2.f*scen*scl;
      }
      if (lane < 16) ws[O_S78T + s*LN + l] = sv;
      float ssum = red16(sv);
      if (lane == 0){
        ws[O_S78S+l] = ssum;
        float y3n, y4n;
        if (pd){
          y3n = fmaxf(ws[O_Y3+l] + sig*( fp - b3l), 0.f);
          y4n = fmaxf(ws[O_Y4+l] + sig*(-fp - b4l), 0.f);
          ws[O_Y3+l] = y3n; ws[O_Y4+l] = y4n;
        } else { y3n = fp*scl; y4n = -fp*scl; }
        ws[O_W34+l] = y3n - y4n + ssum;
      }
    }
  };

  // ---- phase X: PDHG primal update (pd=true) or power AT(ya) (pd=false) ----
  auto phaseX = [&](bool pd, int k){
    if (tid < 20) s_acc[tid] = 0.f;
    __syncthreads();
    float tau = 0.f, scl = 1.f, z1v, z2v, zsv;
    if (pd){
      tau = 0.9f / sqrtf(sqrtf(ws[O_N2+31]));
      z1v = ws[O_Z1];
      z2v = ws[O_Z2 + (lane & 15)];
      zsv = ws[O_ZS];
    } else {
      if (k > 0) scl = 1.f / sqrtf(ws[O_N2+k]);
      z1v = ws[O_EQ1+k]*scl;
      float e2 = (ws[O_EQ2 + k*16 + (lane & 15)] + ws[O_EQS+k])*scl;
      z2v = e2;
      zsv = red16(e2);
    }
    float n2p = 0.f, e1p = 0.f, a2p = 0.f, susdp = 0.f;

    for (int t = gw; t < U + NN; t += NWAVE){
      if (t < U){
        int u = t;
        const float* HT = ws + O_HGT + u*LN;
        float g = 0.f;
        for (int l = lane; l < LN; l += 64) g += HT[l]*ws[O_W34+l];
        float gdot = wred64(g);
        int s = lane & 15, ch = lane >> 4;
        const float* sT = ws + O_S78T + s*LN;
        float h = 0.f;
        int l0 = ch*128;
        for (int l = l0; l < l0+128; ++l) h += HT[l]*sT[l];
        h = redchunk(h);
        float t5 = (lane < 16) ? ws[O_Y5 + u*16 + lane] : 0.f;
        float t6 = (lane < 16) ? ws[O_Y6 + u*16 + lane] : 0.f;
        t5 = red16(t5); t6 = red16(t6);
        if (lane < 16){
          int idx = u*16 + s;
          float y5v = ws[O_Y5+idx], y6v = ws[O_Y6+idx];
          float gpu = y5v + h + z2v;
          float gpd = y6v - h - z2v;
          if (pd){
            float xo = ws[O_XPU+idx]; float xn = fmaxf(xo - tau*gpu, 0.f);
            ws[O_XPU+idx] = xn; float xb1 = 2.f*xn - xo; ws[O_BPU+idx] = xb1;
            xo = ws[O_XPD+idx]; float xn2 = fmaxf(xo - tau*gpd, 0.f);
            ws[O_XPD+idx] = xn2; float xb2 = 2.f*xn2 - xo; ws[O_BPD+idx] = xb2;
            ws[O_DIFF+idx] = xb1 - xb2; a2p += xb1 - xb2;
          } else {
            ws[O_XPU+idx] = gpu; ws[O_XPD+idx] = gpd; ws[O_DIFF+idx] = gpu - gpd;
            n2p += gpu*gpu + gpd*gpd; a2p += gpu - gpd;
          }
        }
        if (lane == 0){
          float y1u = ws[O_Y1+u], y2u = ws[O_Y2+u];
          float gp  = y1u - y2u + gdot + z1v;
          float gru = y1u - t5;
          float grd = y2u - t6;
          if (pd){
            float xo = ws[O_XP+u]; float xn = fmaxf(xo - tau*(Cost[u]+gp), 0.f);
            ws[O_XP+u] = xn; float xb = 2.f*xn - xo; ws[O_BP+u] = xb; e1p += xb;
            xo = ws[O_XRU+u]; xn = fmaxf(xo - tau*(Crup[u]+gru), 0.f);
            ws[O_XRU+u] = xn; ws[O_BRU+u] = 2.f*xn - xo;
            xo = ws[O_XRD+u]; xn = fmaxf(xo - tau*(Crdn[u]+grd), 0.f);
            ws[O_XRD+u] = xn; ws[O_BRD+u] = 2.f*xn - xo;
          } else {
            ws[O_XP+u] = gp; ws[O_XRU+u] = gru; ws[O_XRD+u] = grd;
            n2p += gp*gp + gru*gru + grd*grd; e1p += gp;
          }
        }
      } else {
        int n = t - U;
        const float* PT = ws + O_PTDFT + n*LN;
        float g = 0.f;
        for (int l = lane; l < LN; l += 64) g += PT[l]*ws[O_S78S+l];
        float pt = wred64(g);
        if (lane == 0){
          if (pd){
            float g1 = C_VIOL + pt + zsv;
            float g2 = C_VIOL - pt - zsv;
            float xo = ws[O_XSU+n]; float xn = fmaxf(xo - tau*g1, 0.f);
            ws[O_XSU+n] = xn; float xb1 = 2.f*xn - xo; ws[O_BSU+n] = xb1;
            xo = ws[O_XSD+n]; float xn2 = fmaxf(xo - tau*g2, 0.f);
            ws[O_XSD+n] = xn2; float xb2 = 2.f*xn2 - xo; ws[O_BSD+n] = xb2;
            ws[O_SDIFF+n] = xb1 - xb2; susdp += xb1 - xb2;
          } else {
            float gsu = pt + zsv;
            ws[O_XSU+n] = gsu; ws[O_XSD+n] = -gsu; ws[O_SDIFF+n] = 2.f*gsu;
            n2p += 2.f*gsu*gsu; susdp += 2.f*gsu;
          }
        }
      }
    }
    float r1 = wred64(e1p);
    float r2 = wred64(susdp);
    float r3 = wred64(n2p);
    if (lane == 0){
      atomicAdd(&s_acc[16], r1);
      atomicAdd(&s_acc[17], r2);
      atomicAdd(&s_acc[18], r3);
    }
    if (lane < 16) atomicAdd(&s_acc[lane], a2p);
    __syncthreads();
    if (pd){
      int p = k & 1;
      if (tid < 16) atomicAdd(&ws[O_PAE2 + p*16 + tid], s_acc[tid]);
      else if (tid == 16) atomicAdd(&ws[O_PAE1+p], s_acc[16]);
      else if (tid == 17) atomicAdd(&ws[O_PSUSD+p], s_acc[17]);
    } else {
      if (tid < 16) atomicAdd(&ws[O_EQ2 + (k+1)*16 + tid], s_acc[tid]);
      else if (tid == 16) atomicAdd(&ws[O_EQ1 + (k+1)], s_acc[16]);
      else if (tid == 17) atomicAdd(&ws[O_EQS + (k+1)], s_acc[17]);
      else if (tid == 18) atomicAdd(&ws[O_N2  + (k+1)], s_acc[18]);
    }
  };

  // ---- power iteration: 31 applications of AT(A(.)) with on-read normalization
  for (int kk = 0; kk <= N_POWER; ++kk){
    phaseY(false, kk);   // ya = A(v_k / ||v_k||)
    gbar();
    phaseX(false, kk);   // v_{k+1} = AT(ya); accumulate ||.||^2, eq sums
    gbar();
  }

  // ---- zero PDHG state (x, xb, y, z, s78, parity buffers) ----
  for (int i = gtid; i < O_ZEND - O_MUT; i += NTH) ws[O_MUT + i] = 0.f;
  gbar();

  // ---- PDHG ----
  for (int it = 0; it < N_ITERS; ++it){
    phaseX(true, it);    // x_{n+1} = prox(x - tau*(c+AT(y))), xb = 2x_{n+1}-x
    gbar();
    phaseY(true, it);    // y = proj(y + sig*(A(xb)-b)), z += sig*(ae-be)
    gbar();
  }

  // ---- epilogue ----
  for (int i = gtid; i < U; i += NTH){
    out[i]       = ws[O_XP+i];
    out[U+i]     = ws[O_XRU+i];
    out[2*U+i]   = ws[O_XRD+i];
  }
  for (int i = gtid; i < U*S; i += NTH){
    out[3*U + i]         = ws[O_XPU+i];
    out[3*U + U*S + i]   = ws[O_XPD+i];
  }
  for (int l = gw; l < LN; l += NWAVE){
    const float* Hgr = ws + O_HG + l*U;
    float a = 0.f;
    for (int u2 = lane; u2 < U; u2 += 64) a += Hgr[u2]*ws[O_XP+u2];
    float flow = wred64(a) + ws[O_CF+l];
    if (lane == 0){
      out[3*U + 2*U*S + l]      = Cap[l] - flow;
      out[3*U + 2*U*S + LN + l] = Cap[l] + flow;
    }
  }
  if (blockIdx.x == 0){
    float part = 0.f;
    for (int i = tid; i < U; i += TPB)
      part += Cost[i]*ws[O_XP+i] + Crup[i]*ws[O_XRU+i] + Crdn[i]*ws[O_XRD+i];
    for (int i = tid; i < NN; i += TPB)
      part += C_VIOL*(ws[O_XSU+i] + ws[O_XSD+i]);
    sred[tid] = part; __syncthreads();
    for (int o = TPB/2; o > 0; o >>= 1){
      if (tid < o) sred[tid] += sred[tid+o];
      __syncthreads();
    }
    if (tid == 0) out[3*U + 2*U*S + 2*LN] = sred[0];
  }
}

// ---------------- host entry ----------------
extern "C" void kernel_launch(void* const* d_in, const int* in_sizes, int n_in,
                              void* d_out, int out_size, void* d_ws, size_t ws_size,
                              hipStream_t stream){
  const float* w_scen = (const float*)d_in[0];
  const float* Pmax   = (const float*)d_in[1];
  const float* Cost   = (const float*)d_in[2];
  const float* Crup   = (const float*)d_in[3];
  const float* Crdn   = (const float*)d_in[4];
  const float* PTDF   = (const float*)d_in[5];
  const float* nG     = (const float*)d_in[6];
  const float* nW     = (const float*)d_in[7];
  const float* nL     = (const float*)d_in[8];
  const float* Pd     = (const float*)d_in[9];
  const float* w_exp  = (const float*)d_in[10];
  const float* Cap    = (const float*)d_in[11];
  float* ws  = (float*)d_ws;
  float* out = (float*)d_out;

  k_zero<<<dim3(64),  dim3(256), 0, stream>>>(ws);
  k_pdl <<<dim3(NN),  dim3(64),  0, stream>>>(nL, Pd, ws);
  k_hg  <<<dim3(LN),  dim3(U),   0, stream>>>(PTDF, nG, ws);
  k_hw  <<<dim3(LN),  dim3(W_),  0, stream>>>(PTDF, nW, ws);
  k_tp  <<<dim3(NN),  dim3(256), 0, stream>>>(PTDF, ws);
  k_misc<<<dim3(LN),  dim3(64),  0, stream>>>(PTDF, w_exp, w_scen, Cap, ws);
  k_scal<<<dim3(1),   dim3(256), 0, stream>>>(Pd, w_exp, w_scen, ws);
  k_solver<<<dim3(WGN), dim3(TPB), 0, stream>>>(ws, Pmax, Cost, Crup, Crdn, PTDF, Cap, out);
}

// Round 2
// 11155.540 us; speedup vs baseline: 2.8478x; 2.8478x over previous
//
#include <hip/hip_runtime.h>
#include <math.h>

// ---------------- problem constants ----------------
constexpr int U  = 160;
constexpr int LN = 512;
constexpr int NN = 400;
constexpr int S  = 16;
constexpr int W_ = 64;
constexpr float C_VIOL = 2.0e4f;
constexpr int N_ITERS = 500;
constexpr int N_POWER = 30;

// solver launch shape
#define WGN 128
#define TPB 256
#define NTH (WGN*TPB)
#define NWAVE (WGN*4)   // 512 waves: one line per wave

constexpr int al4(int x){ return (x+3)&~3; }

// ---------------- ws layout (floats) ----------------
constexpr int O_HG    = 0;                 // Hg[LN][U]
constexpr int O_HGT   = O_HG   + LN*U;     // HgT[U][LN]
constexpr int O_PTDFT = O_HGT  + U*LN;     // PTDFT[NN][LN]
constexpr int O_HW    = O_PTDFT+ NN*LN;    // Hw[LN][W]
constexpr int O_PDL   = O_HW   + LN*W_;    // node_L@Pd [NN]
constexpr int O_CF    = al4(O_PDL + NN);   // const_flow [LN]
constexpr int O_B3    = O_CF   + LN;       // Cap-cf
constexpr int O_B4    = O_B3   + LN;       // Cap+cf
constexpr int O_BWS   = O_B4   + LN;       // b_ws[LN][S]
constexpr int O_BE1   = O_BWS  + LN*S;
constexpr int O_BE2   = al4(O_BE1 + 1);    // [S]
constexpr int O_MUT   = al4(O_BE2 + S);    // ---- mutable region starts ----
constexpr int O_XP   = O_MUT;
constexpr int O_XRU  = O_XP  + U;
constexpr int O_XRD  = O_XRU + U;
constexpr int O_XPU  = O_XRD + U;          // [U][S]
constexpr int O_XPD  = O_XPU + U*S;
constexpr int O_XSU  = O_XPD + U*S;        // [NN]
constexpr int O_XSD  = O_XSU + NN;
constexpr int O_XEND = O_XSD + NN;
constexpr int O_BP   = O_XEND;
constexpr int O_BRU  = O_BP  + U;
constexpr int O_BRD  = O_BRU + U;
constexpr int O_BPU  = O_BRD + U;
constexpr int O_BPD  = O_BPU + U*S;
constexpr int O_BSU  = O_BPD + U*S;
constexpr int O_BSD  = O_BSU + NN;
constexpr int O_DIFF = O_BSD + NN;         // xb_pu-xb_pd [U][S]
constexpr int O_SDIFF= O_DIFF+ U*S;        // xb_su-xb_sd [NN]
constexpr int O_Y1 = O_SDIFF + NN;         // [U]
constexpr int O_Y2 = O_Y1 + U;
constexpr int O_Y3 = O_Y2 + U;             // [LN]
constexpr int O_Y4 = O_Y3 + LN;
constexpr int O_Y5 = O_Y4 + LN;            // [U][S]
constexpr int O_Y6 = O_Y5 + U*S;
constexpr int O_Y7 = O_Y6 + U*S;           // [LN][S]
constexpr int O_Y8 = O_Y7 + LN*S;
constexpr int O_Z1 = O_Y8 + LN*S;
constexpr int O_Z2 = al4(O_Z1 + 1);        // [S]
constexpr int O_ZS = O_Z2 + S;
constexpr int O_PAE1 = al4(O_ZS + 1);      // [2]
constexpr int O_PAE2 = O_PAE1 + 2;         // [2][16]
constexpr int O_PSUSD= O_PAE2 + 32;        // [2]
constexpr int O_S78T = al4(O_PSUSD + 2);   // s78 transposed [S][LN]
constexpr int O_S78S = O_S78T + S*LN;      // [LN]
constexpr int O_W34  = O_S78S + LN;        // y3-y4+s78s [LN]
constexpr int O_ZEND = O_W34  + LN;        // ---- zero region end ----
constexpr int O_N2  = O_ZEND;              // [32]
constexpr int O_EQ1 = O_N2  + 32;          // [32]
constexpr int O_EQ2 = O_EQ1 + 32;          // [32][16]
constexpr int O_EQS = O_EQ2 + 32*16;       // [32]
constexpr int O_ARR = O_EQS + 32;          // [WGN] barrier arrival flags
constexpr int O_REL = O_ARR + WGN;         // release word
constexpr int WSF   = O_REL + 1;

// ---------------- LDS layout (floats) ----------------
constexpr int L_HGR  = 0;                  // Hg rows for my 4 lines [4][160]
constexpr int L_B3   = L_HGR + 640;        // [4]
constexpr int L_B4   = L_B3 + 4;
constexpr int L_BWS  = L_B4 + 4;           // [4][16]
constexpr int L_ROWA = L_BWS + 64;         // [4][512] HgT rows (bid<40) / PTDFT rows (bid>=40)
constexpr int L_ROWB = L_ROWA + 2048;      // [4][512] extra PTDFT rows (bid<12)
constexpr int L_DYN  = L_ROWB + 2048;      // phase-dependent region
// phase Y within DYN:
constexpr int L_XP = L_DYN;                // [160]
constexpr int L_SD = L_XP + 160;           // [400]
constexpr int L_DF = L_SD + 400;           // [160][17] padded
// phase X within DYN:
constexpr int D_S78T = L_DYN;              // [16][516] padded
constexpr int D_W34  = D_S78T + 16*516;    // [512]
constexpr int D_S78S = D_W34 + 512;        // [512]
constexpr int L_TOT  = L_DYN + 16*516 + 512 + 512;  // 14088 floats ~56.4KB

// ---------------- device helpers ----------------
__device__ __forceinline__ float wred64(float v){
#pragma unroll
  for (int o = 32; o > 0; o >>= 1) v += __shfl_xor(v, o, 64);
  return v;
}
__device__ __forceinline__ float red16(float v){
  v += __shfl_xor(v, 1, 64); v += __shfl_xor(v, 2, 64);
  v += __shfl_xor(v, 4, 64); v += __shfl_xor(v, 8, 64);
  return v;
}
__device__ __forceinline__ float redchunk(float v){
  v += __shfl_xor(v, 16, 64); v += __shfl_xor(v, 32, 64);
  return v;
}
__device__ __forceinline__ float dot4(float4 a, float4 b){
  return a.x*b.x + a.y*b.y + a.z*b.z + a.w*b.w;
}

// ---------------- setup kernels ----------------
__global__ void k_zero(float* ws){
  int gt = blockIdx.x*blockDim.x + threadIdx.x;
  int nt = gridDim.x*blockDim.x;
  for (int i = gt; i < WSF - O_MUT; i += nt){
    int a = O_MUT + i;
    float v = 0.f;
    if (a >= O_XP && a < O_XEND) v = 1.f;          // power-iteration v0 = ones
    if (a == O_EQ1) v = (float)U;                  // eq1 of ones = sum(p)=U
    ws[a] = v;
  }
}

__global__ void k_pdl(const float* nL, const float* Pd, float* ws){
  int n = blockIdx.x; int lane = threadIdx.x;
  float p = 0.f;
  for (int m = lane; m < NN; m += 64) p += nL[n*NN+m]*Pd[m];
  p = wred64(p);
  if (lane == 0) ws[O_PDL+n] = p;
}

__global__ void k_hg(const float* PTDF, const float* nG, float* ws){
  int l = blockIdx.x, u = threadIdx.x;
  float acc = 0.f;
  for (int n = 0; n < NN; ++n) acc += PTDF[l*NN+n]*nG[n*U+u];
  ws[O_HG + l*U + u]  = acc;
  ws[O_HGT + u*LN + l] = acc;
}

__global__ void k_hw(const float* PTDF, const float* nW, float* ws){
  int l = blockIdx.x, w = threadIdx.x;
  float acc = 0.f;
  for (int n = 0; n < NN; ++n) acc += PTDF[l*NN+n]*nW[n*W_+w];
  ws[O_HW + l*W_ + w] = acc;
}

__global__ void k_tp(const float* PTDF, float* ws){
  int n = blockIdx.x;
  for (int l = threadIdx.x; l < LN; l += blockDim.x)
    ws[O_PTDFT + n*LN + l] = PTDF[l*NN + n];
}

__global__ void k_misc(const float* PTDF, const float* w_exp, const float* w_scen,
                       const float* Cap, float* ws){
  int l = blockIdx.x; int lane = threadIdx.x;
  float part = ws[O_HW + l*W_ + lane]*w_exp[lane];
  for (int n = lane; n < NN; n += 64) part -= PTDF[l*NN+n]*ws[O_PDL+n];
  float cfv = wred64(part);
  if (lane == 0){
    ws[O_CF+l] = cfv;
    ws[O_B3+l] = Cap[l] - cfv;
    ws[O_B4+l] = Cap[l] + cfv;
  }
  int s = lane & 15, ch = lane >> 4;
  float bp = 0.f;
  for (int w = ch*16; w < ch*16+16; ++w) bp += ws[O_HW + l*W_ + w]*w_scen[s*W_+w];
  bp = redchunk(bp);
  if (lane < 16) ws[O_BWS + l*S + s] = bp;
}

__global__ void k_scal(const float* Pd, const float* w_exp, const float* w_scen, float* ws){
  __shared__ float sr[256];
  int tid = threadIdx.x;
  float p = 0.f;
  for (int i = tid; i < NN; i += 256) p += Pd[i];
  for (int i = tid; i < W_; i += 256) p -= w_exp[i];
  sr[tid] = p; __syncthreads();
  for (int o = 128; o > 0; o >>= 1){ if (tid < o) sr[tid] += sr[tid+o]; __syncthreads(); }
  if (tid == 0) ws[O_BE1] = sr[0];
  if (tid < S){
    float a = 0.f;
    for (int w = 0; w < W_; ++w) a += w_scen[tid*W_+w];
    ws[O_BE2+tid] = -a;
  }
}

// ---------------- persistent solver ----------------
extern "C" __global__ void __launch_bounds__(TPB)
k_solver(float* __restrict__ ws, const float* __restrict__ Pmax,
         const float* __restrict__ Cost, const float* __restrict__ Crup,
         const float* __restrict__ Crdn, const float* __restrict__ PTDF,
         const float* __restrict__ Cap, float* __restrict__ out)
{
  const int tid  = threadIdx.x;
  const int lane = tid & 63;
  const int wv   = tid >> 6;
  const int bid  = blockIdx.x;
  const int gw   = bid*4 + wv;         // 0..511 global wave id == line id
  const int gtid = bid*TPB + tid;
  unsigned* arr = (unsigned*)(ws + O_ARR);
  unsigned* rel = (unsigned*)(ws + O_REL);
  unsigned nbar = 0;
  __shared__ __align__(16) float lds[L_TOT];
  __shared__ float s_acc[20];

  // ---- contention-light grid barrier: per-WG flag stores, WG0 aggregates ----
  auto gbar = [&](){
    ++nbar;
    __syncthreads();                   // drains each wave's vmem (HIP emits vmcnt(0))
    if (bid == 0){
      if (tid > 0 && tid < WGN){
        while (__hip_atomic_load(&arr[tid], __ATOMIC_RELAXED, __HIP_MEMORY_SCOPE_AGENT) < nbar)
          __builtin_amdgcn_s_sleep(1);
      }
      __syncthreads();
      if (tid == 0){
        __threadfence();
        __hip_atomic_store(rel, nbar, __ATOMIC_RELAXED, __HIP_MEMORY_SCOPE_AGENT);
      }
      __syncthreads();
    } else {
      if (tid == 0){
        __threadfence();
        __hip_atomic_store(&arr[bid], nbar, __ATOMIC_RELAXED, __HIP_MEMORY_SCOPE_AGENT);
        while (__hip_atomic_load(rel, __ATOMIC_RELAXED, __HIP_MEMORY_SCOPE_AGENT) < nbar)
          __builtin_amdgcn_s_sleep(1);
        __threadfence();
      }
      __syncthreads();
    }
  };

  // ---- persistent LDS init (read-only rows, loaded once) ----
  for (int i = tid; i < 640; i += TPB){
    int w = i/160, u = i - w*160;
    lds[L_HGR + i] = ws[O_HG + (bid*4+w)*U + u];
  }
  if (tid < 4){
    lds[L_B3+tid] = ws[O_B3 + bid*4+tid];
    lds[L_B4+tid] = ws[O_B4 + bid*4+tid];
  }
  if (tid < 64){
    int w = tid >> 4;
    lds[L_BWS+tid] = ws[O_BWS + (bid*4+w)*S + (tid&15)];
  }
  if (bid < 40){
    for (int i = tid; i < 2048; i += TPB){
      int w = i >> 9, u = bid*4 + w;
      lds[L_ROWA + i] = ws[O_HGT + u*LN + (i&511)];
    }
  } else {
    for (int i = tid; i < 2048; i += TPB){
      int w = i >> 9, n = bid*4 + w - 160;
      lds[L_ROWA + i] = ws[O_PTDFT + n*LN + (i&511)];
    }
  }
  if (bid < 12){
    for (int i = tid; i < 2048; i += TPB){
      int w = i >> 9, n = 352 + bid*4 + w;
      lds[L_ROWB + i] = ws[O_PTDFT + n*LN + (i&511)];
    }
  }
  __syncthreads();

  // ---- phase Y: y = A-apply (power) or dual update (pdhg) ----
  auto phaseY = [&](bool pd, int k){
    float scl = 1.f, sig = 0.f;
    if (pd) sig = 0.9f / sqrtf(sqrtf(ws[O_N2+31]));
    else if (k > 0) scl = 1.f / sqrtf(ws[O_N2+k]);

    // stage Xp, SDIFF, DIFF(padded 17) into LDS
    {
      const float4* xs = (const float4*)(ws + (pd ? O_BP : O_XP));
      float4* LX = (float4*)(lds + L_XP);
      for (int i = tid; i < 40; i += TPB) LX[i] = xs[i];
      const float4* sds = (const float4*)(ws + O_SDIFF);
      float4* LS = (float4*)(lds + L_SD);
      for (int i = tid; i < 100; i += TPB) LS[i] = sds[i];
      const float4* dfs = (const float4*)(ws + O_DIFF);
      for (int i = tid; i < 640; i += TPB){
        float4 v = dfs[i];
        int e = i*4; int u = e >> 4, s = e & 15;
        float* d = lds + L_DF + u*17 + s;
        d[0]=v.x; d[1]=v.y; d[2]=v.z; d[3]=v.w;
      }
    }
    __syncthreads();

    // eq-dual z update (pdhg only), WG0 wave0
    if (pd && bid == 0 && wv == 0){
      int p = k & 1, q = 1 - p;
      float zn = 0.f;
      if (lane < 16){
        float ae2 = ws[O_PAE2 + p*16 + lane] + ws[O_PSUSD + p];
        zn = ws[O_Z2+lane] + sig*(ae2 - ws[O_BE2+lane]);
        ws[O_Z2+lane] = zn;
      }
      float zst = red16(zn);
      if (lane == 0){
        ws[O_ZS] = zst;
        ws[O_Z1] = ws[O_Z1] + sig*(ws[O_PAE1+p] - ws[O_BE1]);
      }
      if (lane < 16) ws[O_PAE2 + q*16 + lane] = 0.f;
      if (lane == 16) ws[O_PAE1+q] = 0.f;
      if (lane == 17) ws[O_PSUSD+q] = 0.f;
    }

    // per-u y1/y2 and per-(u,s) y5/y6
    if (gtid < U){
      int u = gtid;
      float xbp = lds[L_XP+u];
      if (pd){
        ws[O_Y1+u] = fmaxf(ws[O_Y1+u] + sig*(xbp + ws[(pd?O_BRU:O_XRU)+u] - Pmax[u]), 0.f);
        ws[O_Y2+u] = fmaxf(ws[O_Y2+u] + sig*(ws[(pd?O_BRD:O_XRD)+u] - xbp), 0.f);
      } else {
        ws[O_Y1+u] = (xbp + ws[O_XRU+u])*scl;
        ws[O_Y2+u] = (ws[O_XRD+u] - xbp)*scl;
      }
    } else if (gtid < U + U*S){
      int idx = gtid - U; int u = idx >> 4;
      if (pd){
        ws[O_Y5+idx] = fmaxf(ws[O_Y5+idx] + sig*(ws[O_BPU+idx] - ws[O_BRU+u]), 0.f);
        ws[O_Y6+idx] = fmaxf(ws[O_Y6+idx] + sig*(ws[O_BPD+idx] - ws[O_BRD+u]), 0.f);
      } else {
        ws[O_Y5+idx] = (ws[O_XPU+idx] - ws[O_XRU+u])*scl;
        ws[O_Y6+idx] = (ws[O_XPD+idx] - ws[O_XRD+u])*scl;
      }
    }

    // per-line: one line per wave
    {
      const int l = gw;
      const float* hg = lds + L_HGR + wv*160;
      float a = hg[lane]*lds[L_XP+lane] + hg[lane+64]*lds[L_XP+lane+64];
      if (lane < 32) a += hg[lane+128]*lds[L_XP+lane+128];
      float fp = wred64(a);

      const float4* pr = (const float4*)(PTDF + l*NN);
      const float4* sd4 = (const float4*)(lds + L_SD);
      float b = dot4(pr[lane], sd4[lane]);
      if (lane < 36) b += dot4(pr[lane+64], sd4[lane+64]);
      float pn = wred64(b);

      int s = lane & 15, ch = lane >> 4;
      const float* hgc = hg + ch*40;
      const float* dfc = lds + L_DF + (ch*40)*17 + s;
      float sc = 0.f;
#pragma unroll 8
      for (int i = 0; i < 40; ++i) sc += hgc[i]*dfc[i*17];
      sc = redchunk(sc);

      float scen = sc + fp + pn;
      float b3l = lds[L_B3+wv], b4l = lds[L_B4+wv];
      float sv;
      if (pd){
        float bw  = lds[L_BWS + wv*16 + s];
        float y7n = fmaxf(ws[O_Y7 + l*16 + s] + sig*( scen - (b3l - bw)), 0.f);
        float y8n = fmaxf(ws[O_Y8 + l*16 + s] + sig*(-scen - (b4l + bw)), 0.f);
        if (lane < 16){ ws[O_Y7 + l*16 + s] = y7n; ws[O_Y8 + l*16 + s] = y8n; }
        sv = y7n - y8n;
      } else {
        sv = 2.f*scen*scl;
      }
      if (lane < 16) ws[O_S78T + s*LN + l] = sv;
      float ssum = red16(sv);
      if (lane == 0){
        ws[O_S78S+l] = ssum;
        float y3n, y4n;
        if (pd){
          y3n = fmaxf(ws[O_Y3+l] + sig*( fp - b3l), 0.f);
          y4n = fmaxf(ws[O_Y4+l] + sig*(-fp - b4l), 0.f);
          ws[O_Y3+l] = y3n; ws[O_Y4+l] = y4n;
        } else { y3n = fp*scl; y4n = -fp*scl; }
        ws[O_W34+l] = y3n - y4n + ssum;
      }
    }
  };

  // ---- phase X: AT-apply + primal update ----
  auto phaseX = [&](bool pd, int k){
    if (tid < 20) s_acc[tid] = 0.f;
    // stage per WG role
    if (bid < 40){
      const float4* st = (const float4*)(ws + O_S78T);
      for (int i = tid; i < 2048; i += TPB){
        float4 v = st[i];
        int e = i*4, s = e >> 9, l = e & 511;
        ((float4*)(lds + D_S78T + s*516))[l >> 2] = v;
      }
      const float4* wsrc = (const float4*)(ws + O_W34);
      float4* dw = (float4*)(lds + D_W34);
      for (int i = tid; i < 128; i += TPB) dw[i] = wsrc[i];
    }
    if (bid < 12 || bid >= 40){
      const float4* ss = (const float4*)(ws + O_S78S);
      float4* ds = (float4*)(lds + D_S78S);
      for (int i = tid; i < 128; i += TPB) ds[i] = ss[i];
    }
    __syncthreads();

    float tau = 0.f, scl = 1.f, z1v, z2v, zsv;
    if (pd){
      tau = 0.9f / sqrtf(sqrtf(ws[O_N2+31]));
      z1v = ws[O_Z1];
      z2v = ws[O_Z2 + (lane & 15)];
      zsv = ws[O_ZS];
    } else {
      if (k > 0) scl = 1.f / sqrtf(ws[O_N2+k]);
      z1v = ws[O_EQ1+k]*scl;
      float e2 = (ws[O_EQ2 + k*16 + (lane & 15)] + ws[O_EQS+k])*scl;
      z2v = e2;
      zsv = red16(e2);
    }
    float n2p = 0.f, e1p = 0.f, a2p = 0.f, susdp = 0.f;

    for (int rep = 0; rep < 2; ++rep){
      if (rep == 1 && gw >= 48) break;
      int t = gw + (rep << 9);
      if (t < U){
        int u = t;
        const float* HT = lds + L_ROWA + wv*512;
        const float4* ht4 = (const float4*)HT;
        const float4* w4 = (const float4*)(lds + D_W34);
        float g = dot4(ht4[lane], w4[lane]) + dot4(ht4[lane+64], w4[lane+64]);
        float gdot = wred64(g);
        int s = lane & 15, ch = lane >> 4;
        const float4* hc4 = (const float4*)(HT + ch*128);
        const float4* sc4 = (const float4*)(lds + D_S78T + s*516 + ch*128);
        float h = 0.f;
#pragma unroll 8
        for (int i = 0; i < 32; ++i) h += dot4(hc4[i], sc4[i]);
        h = redchunk(h);
        float t5 = (lane < 16) ? ws[O_Y5 + u*16 + lane] : 0.f;
        float t6 = (lane < 16) ? ws[O_Y6 + u*16 + lane] : 0.f;
        t5 = red16(t5); t6 = red16(t6);
        if (lane < 16){
          int idx = u*16 + s;
          float y5v = ws[O_Y5+idx], y6v = ws[O_Y6+idx];
          float gpu = y5v + h + z2v;
          float gpd = y6v - h - z2v;
          if (pd){
            float xo = ws[O_XPU+idx]; float xn = fmaxf(xo - tau*gpu, 0.f);
            ws[O_XPU+idx] = xn; float xb1 = 2.f*xn - xo; ws[O_BPU+idx] = xb1;
            xo = ws[O_XPD+idx]; float xn2 = fmaxf(xo - tau*gpd, 0.f);
            ws[O_XPD+idx] = xn2; float xb2 = 2.f*xn2 - xo; ws[O_BPD+idx] = xb2;
            ws[O_DIFF+idx] = xb1 - xb2; a2p += xb1 - xb2;
          } else {
            ws[O_XPU+idx] = gpu; ws[O_XPD+idx] = gpd; ws[O_DIFF+idx] = gpu - gpd;
            n2p += gpu*gpu + gpd*gpd; a2p += gpu - gpd;
          }
        }
        if (lane == 0){
          float y1u = ws[O_Y1+u], y2u = ws[O_Y2+u];
          float gp  = y1u - y2u + gdot + z1v;
          float gru = y1u - t5;
          float grd = y2u - t6;
          if (pd){
            float xo = ws[O_XP+u]; float xn = fmaxf(xo - tau*(Cost[u]+gp), 0.f);
            ws[O_XP+u] = xn; float xb = 2.f*xn - xo; ws[O_BP+u] = xb; e1p += xb;
            xo = ws[O_XRU+u]; xn = fmaxf(xo - tau*(Crup[u]+gru), 0.f);
            ws[O_XRU+u] = xn; ws[O_BRU+u] = 2.f*xn - xo;
            xo = ws[O_XRD+u]; xn = fmaxf(xo - tau*(Crdn[u]+grd), 0.f);
            ws[O_XRD+u] = xn; ws[O_BRD+u] = 2.f*xn - xo;
          } else {
            ws[O_XP+u] = gp; ws[O_XRU+u] = gru; ws[O_XRD+u] = grd;
            n2p += gp*gp + gru*gru + grd*grd; e1p += gp;
          }
        }
      } else if (t < U + NN){
        int n = t - U;
        const float* PT = lds + ((rep == 0) ? L_ROWA : L_ROWB) + wv*512;
        const float4* pt4 = (const float4*)PT;
        const float4* ss4 = (const float4*)(lds + D_S78S);
        float g = dot4(pt4[lane], ss4[lane]) + dot4(pt4[lane+64], ss4[lane+64]);
        float pt = wred64(g);
        if (lane == 0){
          if (pd){
            float g1 = C_VIOL + pt + zsv;
            float g2 = C_VIOL - pt - zsv;
            float xo = ws[O_XSU+n]; float xn = fmaxf(xo - tau*g1, 0.f);
            ws[O_XSU+n] = xn; float xb1 = 2.f*xn - xo; ws[O_BSU+n] = xb1;
            xo = ws[O_XSD+n]; float xn2 = fmaxf(xo - tau*g2, 0.f);
            ws[O_XSD+n] = xn2; float xb2 = 2.f*xn2 - xo; ws[O_BSD+n] = xb2;
            ws[O_SDIFF+n] = xb1 - xb2; susdp += xb1 - xb2;
          } else {
            float gsu = pt + zsv;
            ws[O_XSU+n] = gsu; ws[O_XSD+n] = -gsu; ws[O_SDIFF+n] = 2.f*gsu;
            n2p += 2.f*gsu*gsu; susdp += 2.f*gsu;
          }
        }
      }
    }
    float r1 = wred64(e1p);
    float r2 = wred64(susdp);
    float r3 = wred64(n2p);
    if (lane == 0){
      atomicAdd(&s_acc[16], r1);
      atomicAdd(&s_acc[17], r2);
      atomicAdd(&s_acc[18], r3);
    }
    if (lane < 16) atomicAdd(&s_acc[lane], a2p);
    __syncthreads();
    if (pd){
      int p = k & 1;
      if (tid < 16) atomicAdd(&ws[O_PAE2 + p*16 + tid], s_acc[tid]);
      else if (tid == 16) atomicAdd(&ws[O_PAE1+p], s_acc[16]);
      else if (tid == 17) atomicAdd(&ws[O_PSUSD+p], s_acc[17]);
    } else {
      if (tid < 16) atomicAdd(&ws[O_EQ2 + (k+1)*16 + tid], s_acc[tid]);
      else if (tid == 16) atomicAdd(&ws[O_EQ1 + (k+1)], s_acc[16]);
      else if (tid == 17) atomicAdd(&ws[O_EQS + (k+1)], s_acc[17]);
      else if (tid == 18) atomicAdd(&ws[O_N2  + (k+1)], s_acc[18]);
    }
  };

  // ---- power iteration ----
  for (int kk = 0; kk <= N_POWER; ++kk){
    phaseY(false, kk);
    gbar();
    phaseX(false, kk);
    gbar();
  }

  // ---- zero PDHG state ----
  for (int i = gtid; i < O_ZEND - O_MUT; i += NTH) ws[O_MUT + i] = 0.f;
  gbar();

  // ---- PDHG ----
  for (int it = 0; it < N_ITERS; ++it){
    phaseX(true, it);
    gbar();
    phaseY(true, it);
    gbar();
  }

  // ---- epilogue ----
  for (int i = gtid; i < U; i += NTH){
    out[i]       = ws[O_XP+i];
    out[U+i]     = ws[O_XRU+i];
    out[2*U+i]   = ws[O_XRD+i];
  }
  for (int i = gtid; i < U*S; i += NTH){
    out[3*U + i]         = ws[O_XPU+i];
    out[3*U + U*S + i]   = ws[O_XPD+i];
  }
  {
    const int l = gw;
    const float* hg = lds + L_HGR + wv*160;
    float a = hg[lane]*ws[O_XP+lane] + hg[lane+64]*ws[O_XP+lane+64];
    if (lane < 32) a += hg[lane+128]*ws[O_XP+lane+128];
    float flow = wred64(a) + ws[O_CF+l];
    if (lane == 0){
      out[3*U + 2*U*S + l]      = Cap[l] - flow;
      out[3*U + 2*U*S + LN + l] = Cap[l] + flow;
    }
  }
  if (bid == 0){
    float* sred = lds + D_S78T;  // phases done; reuse dynamic LDS
    float part = 0.f;
    for (int i = tid; i < U; i += TPB)
      part += Cost[i]*ws[O_XP+i] + Crup[i]*ws[O_XRU+i] + Crdn[i]*ws[O_XRD+i];
    for (int i = tid; i < NN; i += TPB)
      part += C_VIOL*(ws[O_XSU+i] + ws[O_XSD+i]);
    __syncthreads();
    sred[tid] = part; __syncthreads();
    for (int o = TPB/2; o > 0; o >>= 1){
      if (tid < o) sred[tid] += sred[tid+o];
      __syncthreads();
    }
    if (tid == 0) out[3*U + 2*U*S + 2*LN] = sred[0];
  }
}

// ---------------- host entry ----------------
extern "C" void kernel_launch(void* const* d_in, const int* in_sizes, int n_in,
                              void* d_out, int out_size, void* d_ws, size_t ws_size,
                              hipStream_t stream){
  const float* w_scen = (const float*)d_in[0];
  const float* Pmax   = (const float*)d_in[1];
  const float* Cost   = (const float*)d_in[2];
  const float* Crup   = (const float*)d_in[3];
  const float* Crdn   = (const float*)d_in[4];
  const float* PTDF   = (const float*)d_in[5];
  const float* nG     = (const float*)d_in[6];
  const float* nW     = (const float*)d_in[7];
  const float* nL     = (const float*)d_in[8];
  const float* Pd     = (const float*)d_in[9];
  const float* w_exp  = (const float*)d_in[10];
  const float* Cap    = (const float*)d_in[11];
  float* ws  = (float*)d_ws;
  float* out = (float*)d_out;

  k_zero<<<dim3(64),  dim3(256), 0, stream>>>(ws);
  k_pdl <<<dim3(NN),  dim3(64),  0, stream>>>(nL, Pd, ws);
  k_hg  <<<dim3(LN),  dim3(U),   0, stream>>>(PTDF, nG, ws);
  k_hw  <<<dim3(LN),  dim3(W_),  0, stream>>>(PTDF, nW, ws);
  k_tp  <<<dim3(NN),  dim3(256), 0, stream>>>(PTDF, ws);
  k_misc<<<dim3(LN),  dim3(64),  0, stream>>>(PTDF, w_exp, w_scen, Cap, ws);
  k_scal<<<dim3(1),   dim3(256), 0, stream>>>(Pd, w_exp, w_scen, ws);
  k_solver<<<dim3(WGN), dim3(TPB), 0, stream>>>(ws, Pmax, Cost, Crup, Crdn, PTDF, Cap, out);
}

// Round 3
// 9926.571 us; speedup vs baseline: 3.2004x; 1.1238x over previous
//
#include <hip/hip_runtime.h>
#include <math.h>

// ---------------- problem constants ----------------
constexpr int U  = 160;
constexpr int LN = 512;
constexpr int NN = 400;
constexpr int S  = 16;
constexpr int W_ = 64;
constexpr float C_VIOL = 2.0e4f;
constexpr int N_ITERS = 500;
constexpr int N_POWER = 30;

#define WGN 128
#define TPB 256
#define NTH (WGN*TPB)

constexpr int al4(int x){ return (x+3)&~3; }

// ---------------- ws layout (floats) ----------------
// read-only (written by setup kernels, plain access)
constexpr int O_HG    = 0;                 // Hg[LN][U]
constexpr int O_HGT   = O_HG   + LN*U;     // HgT[U][LN]
constexpr int O_PTDFT = O_HGT  + U*LN;     // PTDFT[NN][LN]
constexpr int O_HW    = O_PTDFT+ NN*LN;    // Hw[LN][W]
constexpr int O_PDL   = O_HW   + LN*W_;    // node_L@Pd [NN]
constexpr int O_CF    = al4(O_PDL + NN);   // const_flow [LN]
constexpr int O_B3    = O_CF   + LN;
constexpr int O_B4    = O_B3   + LN;
constexpr int O_BWS   = O_B4   + LN;       // b_ws[LN][S]
constexpr int O_BE1   = O_BWS  + LN*S;
constexpr int O_BE2   = al4(O_BE1 + 1);    // [S]
// mutable (agent-scope atomic access only, inside solver)
constexpr int O_MUT   = al4(O_BE2 + S);
constexpr int O_XBP   = O_MUT;             // xb_p [160]
constexpr int O_XFIN  = O_XBP  + 160;      // final p [160]
constexpr int O_DIFF  = O_XFIN + 160;      // [160][16]
constexpr int O_SDIFF = O_DIFF + 2560;     // [400]
constexpr int O_S78   = O_SDIFF+ 400;      // [512][16]
constexpr int O_SW    = O_S78  + 8192;     // [512][2] (w34, s78s)
constexpr int O_Z     = O_SW   + 1024;     // [20]: 0=z1 1=zs 2..17=z2
constexpr int O_PART  = O_Z    + 20;       // [128][20]
constexpr int O_N2    = O_PART + 2560;     // [32]
constexpr int O_EQ1   = O_N2   + 32;       // [32]
constexpr int O_EQ2   = O_EQ1  + 32;       // [32][16]
constexpr int O_EQS   = O_EQ2  + 512;      // [32]
constexpr int O_ARR   = O_EQS  + 32;       // [128] barrier flags
constexpr int WSF     = O_ARR  + 128;

// ---------------- LDS layout (floats) ----------------
constexpr int L_HGR  = 0;                  // [4][160]
constexpr int L_B3   = L_HGR + 640;        // [4]
constexpr int L_B4   = L_B3 + 4;
constexpr int L_BWS  = L_B4 + 4;           // [4][16]
constexpr int L_ROWA = L_BWS + 64;         // [4][512]
constexpr int L_ROWB = L_ROWA + 2048;      // [4][512]
constexpr int L_SACC = L_ROWB + 2048;      // [20]
constexpr int L_DYN  = al4(L_SACC + 20);
// phase Y:
constexpr int L_XP = L_DYN;                // [160]
constexpr int L_SD = L_XP + 160;           // [400]
constexpr int L_DF = L_SD + 400;           // [160][17]
constexpr int L_P  = L_DF + 2720;          // [128][20] (WG0 only)
// phase X:
constexpr int D_S78T = L_DYN;              // [16][516]
constexpr int D_W34  = D_S78T + 16*516;    // [512]
constexpr int D_S78S = D_W34 + 512;        // [512]
constexpr int L_TOT  = D_S78S + 512;       // 14112 floats ~56.4KB

// ---------------- device helpers ----------------
__device__ __forceinline__ float wred64(float v){
#pragma unroll
  for (int o = 32; o > 0; o >>= 1) v += __shfl_xor(v, o, 64);
  return v;
}
__device__ __forceinline__ float red16(float v){
  v += __shfl_xor(v, 1, 64); v += __shfl_xor(v, 2, 64);
  v += __shfl_xor(v, 4, 64); v += __shfl_xor(v, 8, 64);
  return v;
}
__device__ __forceinline__ float redchunk(float v){
  v += __shfl_xor(v, 16, 64); v += __shfl_xor(v, 32, 64);
  return v;
}
__device__ __forceinline__ float dot4(float4 a, float4 b){
  return a.x*b.x + a.y*b.y + a.z*b.z + a.w*b.w;
}
// agent-scope coherent (MALL) accessors — bypass non-coherent L2, no fences
__device__ __forceinline__ float ald(const float* p){
  return __hip_atomic_load(p, __ATOMIC_RELAXED, __HIP_MEMORY_SCOPE_AGENT);
}
__device__ __forceinline__ void ast(float* p, float v){
  __hip_atomic_store(p, v, __ATOMIC_RELAXED, __HIP_MEMORY_SCOPE_AGENT);
}
__device__ __forceinline__ float2 ald2(const float* p){
  unsigned long long q = __hip_atomic_load((const unsigned long long*)p,
                          __ATOMIC_RELAXED, __HIP_MEMORY_SCOPE_AGENT);
  union { unsigned long long q; float2 f; } c; c.q = q; return c.f;
}
__device__ __forceinline__ void ast2(float* p, float2 v){
  union { float2 f; unsigned long long q; } c; c.f = v;
  __hip_atomic_store((unsigned long long*)p, c.q,
                     __ATOMIC_RELAXED, __HIP_MEMORY_SCOPE_AGENT);
}
__device__ __forceinline__ unsigned aldu(const unsigned* p){
  return __hip_atomic_load(p, __ATOMIC_RELAXED, __HIP_MEMORY_SCOPE_AGENT);
}
__device__ __forceinline__ void astu(unsigned* p, unsigned v){
  __hip_atomic_store(p, v, __ATOMIC_RELAXED, __HIP_MEMORY_SCOPE_AGENT);
}

// ---------------- setup kernels ----------------
__global__ void k_zero(float* ws){
  int gt = blockIdx.x*blockDim.x + threadIdx.x;
  int nt = gridDim.x*blockDim.x;
  for (int i = gt; i < WSF - O_MUT; i += nt){
    int a = O_MUT + i;
    float v = 0.f;
    if (a >= O_XBP && a < O_XBP + 160) v = 1.f;   // power v0: p = ones
    if (a == O_EQ1) v = (float)U;                 // eq1(ones) = sum p = 160
    ws[a] = v;
  }
}

__global__ void k_pdl(const float* nL, const float* Pd, float* ws){
  int n = blockIdx.x; int lane = threadIdx.x;
  float p = 0.f;
  for (int m = lane; m < NN; m += 64) p += nL[n*NN+m]*Pd[m];
  p = wred64(p);
  if (lane == 0) ws[O_PDL+n] = p;
}

__global__ void k_hg(const float* PTDF, const float* nG, float* ws){
  int l = blockIdx.x, u = threadIdx.x;
  float acc = 0.f;
  for (int n = 0; n < NN; ++n) acc += PTDF[l*NN+n]*nG[n*U+u];
  ws[O_HG + l*U + u]  = acc;
  ws[O_HGT + u*LN + l] = acc;
}

__global__ void k_hw(const float* PTDF, const float* nW, float* ws){
  int l = blockIdx.x, w = threadIdx.x;
  float acc = 0.f;
  for (int n = 0; n < NN; ++n) acc += PTDF[l*NN+n]*nW[n*W_+w];
  ws[O_HW + l*W_ + w] = acc;
}

__global__ void k_tp(const float* PTDF, float* ws){
  int n = blockIdx.x;
  for (int l = threadIdx.x; l < LN; l += blockDim.x)
    ws[O_PTDFT + n*LN + l] = PTDF[l*NN + n];
}

__global__ void k_misc(const float* PTDF, const float* w_exp, const float* w_scen,
                       const float* Cap, float* ws){
  int l = blockIdx.x; int lane = threadIdx.x;
  float part = ws[O_HW + l*W_ + lane]*w_exp[lane];
  for (int n = lane; n < NN; n += 64) part -= PTDF[l*NN+n]*ws[O_PDL+n];
  float cfv = wred64(part);
  if (lane == 0){
    ws[O_CF+l] = cfv;
    ws[O_B3+l] = Cap[l] - cfv;
    ws[O_B4+l] = Cap[l] + cfv;
  }
  int s = lane & 15, ch = lane >> 4;
  float bp = 0.f;
  for (int w = ch*16; w < ch*16+16; ++w) bp += ws[O_HW + l*W_ + w]*w_scen[s*W_+w];
  bp = redchunk(bp);
  if (lane < 16) ws[O_BWS + l*S + s] = bp;
}

__global__ void k_scal(const float* Pd, const float* w_exp, const float* w_scen, float* ws){
  __shared__ float sr[256];
  int tid = threadIdx.x;
  float p = 0.f;
  for (int i = tid; i < NN; i += 256) p += Pd[i];
  for (int i = tid; i < W_; i += 256) p -= w_exp[i];
  sr[tid] = p; __syncthreads();
  for (int o = 128; o > 0; o >>= 1){ if (tid < o) sr[tid] += sr[tid+o]; __syncthreads(); }
  if (tid == 0) ws[O_BE1] = sr[0];
  if (tid < S){
    float a = 0.f;
    for (int w = 0; w < W_; ++w) a += w_scen[tid*W_+w];
    ws[O_BE2+tid] = -a;
  }
}

// ---------------- persistent solver ----------------
extern "C" __global__ void __launch_bounds__(TPB)
k_solver(float* __restrict__ ws, const float* __restrict__ Pmax,
         const float* __restrict__ Cost, const float* __restrict__ Crup,
         const float* __restrict__ Crdn, const float* __restrict__ PTDF,
         const float* __restrict__ Cap, float* __restrict__ out)
{
  const int tid  = threadIdx.x;
  const int lane = tid & 63;
  const int wv   = tid >> 6;
  const int bid  = blockIdx.x;
  const int gw   = bid*4 + wv;        // 0..511: line id; u id if <160
  const int gtid = bid*TPB + tid;
  const int s = lane & 15, ch = lane >> 4;
  unsigned nbar = 0;
  __shared__ __align__(16) float lds[L_TOT];

  const bool isU = (gw < U);
  const int  u   = gw;
  const bool hasN0 = (gw >= U + 0) && (gw >= 160);  // n0 = gw-160
  const bool hasN1 = (gw < 48);                      // n1 = gw+352

  float pmax_u=0.f, cost_u=0.f, crup_u=0.f, crdn_u=0.f;
  if (isU){ pmax_u=Pmax[u]; cost_u=Cost[u]; crup_u=Crup[u]; crdn_u=Crdn[u]; }

  // persistent register state
  float xp=1.f,xru=1.f,xrd=1.f,xpu=1.f,xpd=1.f;     // power v0 = ones
  float xsu0=1.f,xsd0=1.f,xsu1=1.f,xsd1=1.f;
  float ry1=0.f,ry2=0.f,ry5=0.f,ry6=0.f;            // pdhg duals (u-wave)
  float ly3=0.f,ly4=0.f,ly7=0.f,ly8=0.f;            // pdhg duals (line-wave)
  float rz1=0.f,rz2=0.f;                             // z (WG0 wave3 only)
  float tau=0.f, sig=0.f;

  // ---- fence-free all-to-all grid barrier ----
  unsigned* arr = (unsigned*)(ws + O_ARR);
  auto gbar = [&](){
    ++nbar;
    __syncthreads();                       // drains vmcnt -> all agent stores acked
    if (tid < WGN){
      if (tid == bid) astu(&arr[bid], nbar);
      while (aldu(&arr[tid]) < nbar) {}
    }
    __syncthreads();
  };

  // ---- persistent LDS init ----
  for (int i = tid; i < 640; i += TPB){
    int w = i/160, uu = i - w*160;
    lds[L_HGR + i] = ws[O_HG + (bid*4+w)*U + uu];
  }
  if (tid < 4){
    lds[L_B3+tid] = ws[O_B3 + bid*4+tid];
    lds[L_B4+tid] = ws[O_B4 + bid*4+tid];
  }
  if (tid < 64){
    int w = tid >> 4;
    lds[L_BWS+tid] = ws[O_BWS + (bid*4+w)*S + (tid&15)];
  }
  if (bid < 40){
    for (int i = tid; i < 2048; i += TPB){
      int w = i >> 9;
      lds[L_ROWA + i] = ws[O_HGT + (bid*4+w)*LN + (i&511)];
    }
  } else {
    for (int i = tid; i < 2048; i += TPB){
      int w = i >> 9;
      lds[L_ROWA + i] = ws[O_PTDFT + (bid*4+w-160)*LN + (i&511)];
    }
  }
  if (bid < 12){
    for (int i = tid; i < 2048; i += TPB){
      int w = i >> 9;
      lds[L_ROWB + i] = ws[O_PTDFT + (352 + bid*4 + w)*LN + (i&511)];
    }
  }
  __syncthreads();

  // ---- phase Y: per-line A-parts (power) / per-line dual update (pdhg) ----
  auto phaseY = [&](bool pd, int k){
    float scl = 1.f;
    if (!pd && k > 0) scl = 1.f/sqrtf(ald(ws+O_N2+k));
    // stage exchange data
    for (int i = tid; i < 80; i += TPB){
      float2 v = ald2(ws+O_XBP+2*i); lds[L_XP+2*i]=v.x; lds[L_XP+2*i+1]=v.y;
    }
    for (int i = tid; i < 200; i += TPB){
      float2 v = ald2(ws+O_SDIFF+2*i); lds[L_SD+2*i]=v.x; lds[L_SD+2*i+1]=v.y;
    }
    for (int i = tid; i < 1280; i += TPB){
      int e = 2*i, uu = e >> 4, ss = e & 15;
      float2 v = ald2(ws+O_DIFF+e);
      float* d = lds + L_DF + uu*17 + ss; d[0]=v.x; d[1]=v.y;
    }
    if (pd && bid == 0){
      for (int i = tid; i < 1280; i += TPB){
        float2 v = ald2(ws+O_PART+2*i); lds[L_P+2*i]=v.x; lds[L_P+2*i+1]=v.y;
      }
    }
    __syncthreads();

    const int l = gw;
    const float* hg = lds + L_HGR + wv*160;
    float a = hg[lane]*lds[L_XP+lane] + hg[lane+64]*lds[L_XP+lane+64];
    if (lane < 32) a += hg[lane+128]*lds[L_XP+lane+128];
    float fp = wred64(a);
    const float4* pr  = (const float4*)(PTDF + l*NN);
    const float4* sd4 = (const float4*)(lds + L_SD);
    float b = dot4(pr[lane], sd4[lane]);
    if (lane < 36) b += dot4(pr[lane+64], sd4[lane+64]);
    float pn = wred64(b);
    const float* hgc = hg + ch*40;
    const float* dfc = lds + L_DF + (ch*40)*17 + s;
    float sc = 0.f;
#pragma unroll 8
    for (int i = 0; i < 40; ++i) sc += hgc[i]*dfc[i*17];
    sc = redchunk(sc);
    float scen = sc + fp + pn;
    float b3l = lds[L_B3+wv], b4l = lds[L_B4+wv];
    float sv;
    if (pd){
      float bw = lds[L_BWS + wv*16 + s];
      ly7 = fmaxf(ly7 + sig*( scen - (b3l - bw)), 0.f);
      ly8 = fmaxf(ly8 + sig*(-scen - (b4l + bw)), 0.f);
      sv = ly7 - ly8;
      ly3 = fmaxf(ly3 + sig*( fp - b3l), 0.f);
      ly4 = fmaxf(ly4 + sig*(-fp - b4l), 0.f);
    } else {
      sv = 2.f*scen*scl;
      ly3 = fp*scl; ly4 = -fp*scl;
    }
    if (lane < 16) ast(ws+O_S78+l*16+s, sv);
    float ssum = red16(sv);
    float w34 = ly3 - ly4 + ssum;
    if (lane == 0) ast2(ws+O_SW+2*l, make_float2(w34, ssum));

    // WG0 wave3: z-update from PART partials (pdhg only)
    if (pd && bid == 0 && wv == 3){
      float acc = 0.f;
      if (lane < 18){
        for (int i = 0; i < 128; ++i) acc += lds[L_P + i*20 + lane];
      }
      float susd = __shfl(acc, 17, 64);
      float ae1  = __shfl(acc, 16, 64);
      if (lane < 16){
        rz2 = rz2 + sig*((acc + susd) - ws[O_BE2+lane]);
        ast(ws+O_Z+2+lane, rz2);
      }
      float zst = red16((lane < 16) ? rz2 : 0.f);
      if (lane == 0) ast(ws+O_Z+1, zst);
      if (lane == 16){
        rz1 = rz1 + sig*(ae1 - ws[O_BE1]);
        ast(ws+O_Z+0, rz1);
      }
    }
  };

  // ---- phase X: AT-apply + primal update (+local dual updates) ----
  auto phaseX = [&](bool pd, int k, bool last){
    if (tid < 20) lds[L_SACC+tid] = 0.f;
    if (bid < 40){
      for (int i = tid; i < 512; i += TPB){
        float2 v = ald2(ws+O_SW+2*i);
        lds[D_W34+i] = v.x;
        if (bid < 12) lds[D_S78S+i] = v.y;
      }
      for (int i = tid; i < 4096; i += TPB){
        int e = 2*i, ll = e >> 4, ss = e & 15;
        float2 v = ald2(ws+O_S78+e);
        lds[D_S78T + ss*516 + ll] = v.x;
        lds[D_S78T + (ss+1)*516 + ll] = v.y;
      }
    } else {
      for (int i = tid; i < 512; i += TPB){
        float2 v = ald2(ws+O_SW+2*i); lds[D_S78S+i] = v.y;
      }
    }
    float scl = 1.f, z1v, z2v, zsv;
    if (pd){
      z1v = ald(ws+O_Z+0);
      z2v = ald(ws+O_Z+2+s);
      zsv = ald(ws+O_Z+1);
    } else {
      if (k > 0) scl = 1.f/sqrtf(ald(ws+O_N2+k));
      z1v = ald(ws+O_EQ1+k)*scl;
      z2v = (ald(ws+O_EQ2+k*16+s) + ald(ws+O_EQS+k))*scl;
      zsv = red16(z2v);
    }
    __syncthreads();

    float n2p=0.f, e1p=0.f, a2p=0.f, susdp=0.f, dap=0.f;
    if (isU){
      float y1,y2,y5,y6;
      if (pd){ y1=ry1; y2=ry2; y5=ry5; y6=ry6; }
      else {
        y1=(xp+xru)*scl; y2=(xrd-xp)*scl;
        y5=(xpu-xru)*scl; y6=(xpd-xrd)*scl;
      }
      const float* HT = lds + L_ROWA + wv*512;
      const float4* ht4 = (const float4*)HT;
      const float4* w4  = (const float4*)(lds + D_W34);
      float g = dot4(ht4[lane], w4[lane]) + dot4(ht4[lane+64], w4[lane+64]);
      float gdot = wred64(g);
      const float4* hc4 = (const float4*)(HT + ch*128);
      const float4* sc4 = (const float4*)(lds + D_S78T + s*516 + ch*128);
      float h = 0.f;
#pragma unroll 8
      for (int i = 0; i < 32; ++i) h += dot4(hc4[i], sc4[i]);
      h = redchunk(h);
      float t5 = wred64((lane < 16) ? y5 : 0.f);
      float t6 = wred64((lane < 16) ? y6 : 0.f);
      float gpu = y5 + h + z2v;
      float gpd = y6 - h - z2v;
      float gp  = y1 - y2 + gdot + z1v;
      float gru = y1 - t5;
      float grd = y2 - t6;
      if (pd){
        float xo;
        xo=xp;  xp =fmaxf(xo - tau*(cost_u+gp ), 0.f); float xbp_ = 2.f*xp  - xo;
        xo=xru; xru=fmaxf(xo - tau*(crup_u+gru), 0.f); float xbru = 2.f*xru - xo;
        xo=xrd; xrd=fmaxf(xo - tau*(crdn_u+grd), 0.f); float xbrd = 2.f*xrd - xo;
        xo=xpu; xpu=fmaxf(xo - tau*gpu, 0.f);          float xbpu = 2.f*xpu - xo;
        xo=xpd; xpd=fmaxf(xo - tau*gpd, 0.f);          float xbpd = 2.f*xpd - xo;
        float d = xbpu - xbpd;
        if (lane == 0){ ast(ws+O_XBP+u, xbp_); e1p += xbp_; }
        if (lane < 16){ ast(ws+O_DIFF+u*16+s, d); a2p += d; }
        ry1 = fmaxf(y1 + sig*(xbp_ + xbru - pmax_u), 0.f);
        ry2 = fmaxf(y2 + sig*(xbrd - xbp_), 0.f);
        ry5 = fmaxf(y5 + sig*(xbpu - xbru), 0.f);
        ry6 = fmaxf(y6 + sig*(xbpd - xbrd), 0.f);
        if (last){
          if (lane == 0){
            ast(ws+O_XFIN+u, xp);
            dap += cost_u*xp + crup_u*xru + crdn_u*xrd;
            out[u] = xp; out[U+u] = xru; out[2*U+u] = xrd;
          }
          if (lane < 16){
            out[3*U + u*16 + s] = xpu;
            out[3*U + U*S + u*16 + s] = xpd;
          }
        }
      } else {
        xp=gp; xru=gru; xrd=grd; xpu=gpu; xpd=gpd;
        float d = gpu - gpd;
        if (lane == 0){ ast(ws+O_XBP+u, gp); e1p += gp; n2p += gp*gp+gru*gru+grd*grd; }
        if (lane < 16){ ast(ws+O_DIFF+u*16+s, d); a2p += d; n2p += gpu*gpu+gpd*gpd; }
      }
    }
    // n-work
    {
      const float4* ss4 = (const float4*)(lds + D_S78S);
      auto nwork = [&](int n, const float* PTrow, float& xsu, float& xsd){
        const float4* pt4 = (const float4*)PTrow;
        float g = dot4(pt4[lane], ss4[lane]) + dot4(pt4[lane+64], ss4[lane+64]);
        float pt = wred64(g);
        if (pd){
          float g1 = C_VIOL + pt + zsv, g2 = C_VIOL - pt - zsv;
          float xo = xsu; xsu = fmaxf(xo - tau*g1, 0.f); float xb1 = 2.f*xsu - xo;
          xo = xsd;       xsd = fmaxf(xo - tau*g2, 0.f); float xb2 = 2.f*xsd - xo;
          if (lane == 0){
            ast(ws+O_SDIFF+n, xb1-xb2); susdp += xb1-xb2;
            if (last) dap += C_VIOL*(xsu + xsd);
          }
        } else {
          float gsu = pt + zsv;
          xsu = gsu; xsd = -gsu;
          if (lane == 0){ ast(ws+O_SDIFF+n, 2.f*gsu); susdp += 2.f*gsu; n2p += 2.f*gsu*gsu; }
        }
      };
      if (gw >= 160) nwork(gw-160, lds + L_ROWA + wv*512, xsu0, xsd0);
      if (hasN1)     nwork(gw+352, lds + L_ROWB + wv*512, xsu1, xsd1);
    }
    float r1 = wred64(e1p);
    float r2 = wred64(susdp);
    float r3 = wred64(n2p + dap);
    if (lane == 0){
      atomicAdd(&lds[L_SACC+16], r1);
      atomicAdd(&lds[L_SACC+17], r2);
      atomicAdd(&lds[L_SACC+18], r3);
    }
    if (lane < 16) atomicAdd(&lds[L_SACC+s], a2p);
    __syncthreads();
    if (pd){
      if (tid < 10)
        ast2(ws+O_PART+bid*20+2*tid, make_float2(lds[L_SACC+2*tid], lds[L_SACC+2*tid+1]));
    } else {
      if (tid < 16) atomicAdd(&ws[O_EQ2+(k+1)*16+tid], lds[L_SACC+tid]);
      else if (tid == 16) atomicAdd(&ws[O_EQ1+k+1], lds[L_SACC+16]);
      else if (tid == 17) atomicAdd(&ws[O_EQS+k+1], lds[L_SACC+17]);
      else if (tid == 18) atomicAdd(&ws[O_N2 +k+1], lds[L_SACC+18]);
    }
  };

  // ---- power iteration ----
  for (int kk = 0; kk <= N_POWER; ++kk){
    phaseY(false, kk); gbar();
    phaseX(false, kk, false); gbar();
  }

  // ---- step sizes ----
  {
    float Lop = sqrtf(sqrtf(ald(ws+O_N2+31)));
    tau = 0.9f/Lop; sig = 0.9f/Lop;
  }

  // ---- transition: zero register state + exchange buffers ----
  xp=xru=xrd=xpu=xpd=0.f; xsu0=xsd0=xsu1=xsd1=0.f;
  ry1=ry2=ry5=ry6=0.f; ly3=ly4=ly7=ly8=0.f; rz1=rz2=0.f;
  for (int i = gtid; i < 8192+1024+20; i += NTH) ast(ws+O_S78+i, 0.f);
  gbar();

  // ---- PDHG ----
  for (int it = 0; it < N_ITERS; ++it){
    phaseX(true, it, it == N_ITERS-1); gbar();
    if (it < N_ITERS-1){ phaseY(true, it); gbar(); }
  }

  // ---- epilogue: flows + DA cost ----
  for (int i = tid; i < 80; i += TPB){
    float2 v = ald2(ws+O_XFIN+2*i); lds[L_XP+2*i]=v.x; lds[L_XP+2*i+1]=v.y;
  }
  __syncthreads();
  {
    const int l = gw;
    const float* hg = lds + L_HGR + wv*160;
    float a = hg[lane]*lds[L_XP+lane] + hg[lane+64]*lds[L_XP+lane+64];
    if (lane < 32) a += hg[lane+128]*lds[L_XP+lane+128];
    float flow = wred64(a) + ws[O_CF+l];
    if (lane == 0){
      out[3*U + 2*U*S + l]      = Cap[l] - flow;
      out[3*U + 2*U*S + LN + l] = Cap[l] + flow;
    }
  }
  if (bid == 0){
    float da = 0.f;
    if (tid < 128) da = ald(ws+O_PART+tid*20+18);
    da = wred64(da);
    __syncthreads();
    if (lane == 0 && tid < 128) lds[L_SACC + (tid>>6)] = da;
    __syncthreads();
    if (tid == 0) out[3*U + 2*U*S + 2*LN] = lds[L_SACC] + lds[L_SACC+1];
  }
}

// ---------------- host entry ----------------
extern "C" void kernel_launch(void* const* d_in, const int* in_sizes, int n_in,
                              void* d_out, int out_size, void* d_ws, size_t ws_size,
                              hipStream_t stream){
  const float* w_scen = (const float*)d_in[0];
  const float* Pmax   = (const float*)d_in[1];
  const float* Cost   = (const float*)d_in[2];
  const float* Crup   = (const float*)d_in[3];
  const float* Crdn   = (const float*)d_in[4];
  const float* PTDF   = (const float*)d_in[5];
  const float* nG     = (const float*)d_in[6];
  const float* nW     = (const float*)d_in[7];
  const float* nL     = (const float*)d_in[8];
  const float* Pd     = (const float*)d_in[9];
  const float* w_exp  = (const float*)d_in[10];
  const float* Cap    = (const float*)d_in[11];
  float* ws  = (float*)d_ws;
  float* out = (float*)d_out;

  k_zero<<<dim3(64),  dim3(256), 0, stream>>>(ws);
  k_pdl <<<dim3(NN),  dim3(64),  0, stream>>>(nL, Pd, ws);
  k_hg  <<<dim3(LN),  dim3(U),   0, stream>>>(PTDF, nG, ws);
  k_hw  <<<dim3(LN),  dim3(W_),  0, stream>>>(PTDF, nW, ws);
  k_tp  <<<dim3(NN),  dim3(256), 0, stream>>>(PTDF, ws);
  k_misc<<<dim3(LN),  dim3(64),  0, stream>>>(PTDF, w_exp, w_scen, Cap, ws);
  k_scal<<<dim3(1),   dim3(256), 0, stream>>>(Pd, w_exp, w_scen, ws);
  k_solver<<<dim3(WGN), dim3(TPB), 0, stream>>>(ws, Pmax, Cost, Crup, Crdn, PTDF, Cap, out);
}

// Round 4
// 8482.463 us; speedup vs baseline: 3.7452x; 1.1702x over previous
//
#include <hip/hip_runtime.h>
#include <math.h>

// ---------------- problem constants ----------------
constexpr int U  = 160;
constexpr int LN = 512;
constexpr int NN = 400;
constexpr int S  = 16;
constexpr int W_ = 64;
constexpr float C_VIOL = 2.0e4f;
constexpr int N_ITERS = 500;
constexpr int N_POWER = 30;

#define WGN 32
#define TPB 512
#define NTH (WGN*TPB)

constexpr int al4(int x){ return (x+3)&~3; }

// ---------------- ws layout (floats) ----------------
// read-only after setup (plain cached loads inside solver)
constexpr int O_HG    = 0;                 // Hg[LN][U]
constexpr int O_HGT   = O_HG   + LN*U;     // HgT[U][LN]
constexpr int O_PTDFT = O_HGT  + U*LN;     // PTDFT[NN][LN]
constexpr int O_HW    = O_PTDFT+ NN*LN;    // Hw[LN][W]
constexpr int O_PDL   = O_HW   + LN*W_;    // node_L@Pd [NN]
constexpr int O_CF    = al4(O_PDL + NN);   // const_flow [LN]
constexpr int O_B3    = O_CF   + LN;
constexpr int O_B4    = O_B3   + LN;
constexpr int O_BWS   = O_B4   + LN;       // b_ws[LN][S]
constexpr int O_BE1   = O_BWS  + LN*S;
constexpr int O_BE2   = al4(O_BE1 + 1);    // [S]
// mutable exchange (coherent access only inside solver)
constexpr int O_MUT   = al4(O_BE2 + S);
constexpr int O_XBP   = O_MUT;             // [160] xb_p
constexpr int O_XFIN  = O_XBP  + 160;      // [160] final p
constexpr int O_DIFF  = O_XFIN + 160;      // [160][16]
constexpr int O_SDIFF = O_DIFF + 2560;     // [400]
constexpr int O_S78   = al4(O_SDIFF+400);  // [512][16]
constexpr int O_SW    = O_S78  + 8192;     // [512][2]: (w34, s78s)
constexpr int O_Z     = O_SW   + 1024;     // [20]: 0=z1 1=zs 2..17=z2
constexpr int O_PART  = O_Z    + 20;       // [32][20]
constexpr int O_ZEND  = O_PART + 640;      // end of PDHG zero region (S78..PART)
constexpr int O_N2    = O_ZEND;            // [32]
constexpr int O_EQ1   = O_N2   + 32;       // [32]
constexpr int O_EQ2   = O_EQ1  + 32;       // [32][16]
constexpr int O_EQS   = O_EQ2  + 512;      // [32]
constexpr int O_ARR   = O_EQS  + 32;       // [32*16] padded barrier flags
constexpr int WSF     = O_ARR  + WGN*16;

// ---------------- LDS layout (floats) ----------------
constexpr int L_SACC = 0;                  // [20]
constexpr int L_P    = al4(L_SACC + 20);   // [32][20] (WG0 stage of PART)
constexpr int L_DYN  = al4(L_P + 640);
// phase Y:
constexpr int L_XP = L_DYN;                // [160]
constexpr int L_SD = L_XP + 160;           // [400]
constexpr int L_DF = L_SD + 400;           // [160][17]
// phase X:
constexpr int D_S78T = L_DYN;              // [16][516]
constexpr int D_W34  = D_S78T + 16*516;    // [512]
constexpr int D_S78S = D_W34 + 512;        // [512]
constexpr int L_TOT  = D_S78S + 512;       // ~9.9K floats ~40KB

// ---------------- device helpers ----------------
typedef __attribute__((ext_vector_type(4))) float fx4;

__device__ __forceinline__ float wred64(float v){
#pragma unroll
  for (int o = 32; o > 0; o >>= 1) v += __shfl_xor(v, o, 64);
  return v;
}
__device__ __forceinline__ float red16(float v){
  v += __shfl_xor(v, 1, 64); v += __shfl_xor(v, 2, 64);
  v += __shfl_xor(v, 4, 64); v += __shfl_xor(v, 8, 64);
  return v;
}
__device__ __forceinline__ float redchunk(float v){
  v += __shfl_xor(v, 16, 64); v += __shfl_xor(v, 32, 64);
  return v;
}
__device__ __forceinline__ float dot4(float4 a, float4 b){
  return a.x*b.x + a.y*b.y + a.z*b.z + a.w*b.w;
}
// agent-scope coherent accessors
__device__ __forceinline__ float ald(const float* p){
  return __hip_atomic_load(p, __ATOMIC_RELAXED, __HIP_MEMORY_SCOPE_AGENT);
}
__device__ __forceinline__ void ast(float* p, float v){
  __hip_atomic_store(p, v, __ATOMIC_RELAXED, __HIP_MEMORY_SCOPE_AGENT);
}
__device__ __forceinline__ float2 ald2(const float* p){
  unsigned long long q = __hip_atomic_load((const unsigned long long*)p,
                          __ATOMIC_RELAXED, __HIP_MEMORY_SCOPE_AGENT);
  union { unsigned long long q; float2 f; } c; c.q = q; return c.f;
}
__device__ __forceinline__ void ast2(float* p, float2 v){
  union { float2 f; unsigned long long q; } c; c.f = v;
  __hip_atomic_store((unsigned long long*)p, c.q,
                     __ATOMIC_RELAXED, __HIP_MEMORY_SCOPE_AGENT);
}
__device__ __forceinline__ unsigned aldu(const unsigned* p){
  return __hip_atomic_load(p, __ATOMIC_RELAXED, __HIP_MEMORY_SCOPE_AGENT);
}
__device__ __forceinline__ void astu(unsigned* p, unsigned v){
  __hip_atomic_store(p, v, __ATOMIC_RELAXED, __HIP_MEMORY_SCOPE_AGENT);
}

#if defined(__has_builtin)
#if __has_builtin(__builtin_amdgcn_make_buffer_rsrc) && __has_builtin(__builtin_amdgcn_raw_ptr_buffer_load_b128)
#define HAVE_BLD4 1
#endif
#endif

// ---------------- setup kernels ----------------
__global__ void k_zero(float* ws){
  int gt = blockIdx.x*blockDim.x + threadIdx.x;
  int nt = gridDim.x*blockDim.x;
  for (int i = gt; i < WSF - O_MUT; i += nt){
    int a = O_MUT + i;
    float v = 0.f;
    if (a >= O_XBP && a < O_XBP + 160) v = 1.f;   // power v0: p = ones
    if (a == O_EQ1) v = (float)U;                 // eq1(ones) = sum p
    ws[a] = v;
  }
}

__global__ void k_pdl(const float* nL, const float* Pd, float* ws){
  int n = blockIdx.x; int lane = threadIdx.x;
  float p = 0.f;
  for (int m = lane; m < NN; m += 64) p += nL[n*NN+m]*Pd[m];
  p = wred64(p);
  if (lane == 0) ws[O_PDL+n] = p;
}

__global__ void k_hg(const float* PTDF, const float* nG, float* ws){
  int l = blockIdx.x, u = threadIdx.x;
  float acc = 0.f;
  for (int n = 0; n < NN; ++n) acc += PTDF[l*NN+n]*nG[n*U+u];
  ws[O_HG + l*U + u]  = acc;
  ws[O_HGT + u*LN + l] = acc;
}

__global__ void k_hw(const float* PTDF, const float* nW, float* ws){
  int l = blockIdx.x, w = threadIdx.x;
  float acc = 0.f;
  for (int n = 0; n < NN; ++n) acc += PTDF[l*NN+n]*nW[n*W_+w];
  ws[O_HW + l*W_ + w] = acc;
}

__global__ void k_tp(const float* PTDF, float* ws){
  int n = blockIdx.x;
  for (int l = threadIdx.x; l < LN; l += blockDim.x)
    ws[O_PTDFT + n*LN + l] = PTDF[l*NN + n];
}

__global__ void k_misc(const float* PTDF, const float* w_exp, const float* w_scen,
                       const float* Cap, float* ws){
  int l = blockIdx.x; int lane = threadIdx.x;
  float part = ws[O_HW + l*W_ + lane]*w_exp[lane];
  for (int n = lane; n < NN; n += 64) part -= PTDF[l*NN+n]*ws[O_PDL+n];
  float cfv = wred64(part);
  if (lane == 0){
    ws[O_CF+l] = cfv;
    ws[O_B3+l] = Cap[l] - cfv;
    ws[O_B4+l] = Cap[l] + cfv;
  }
  int s = lane & 15, ch = lane >> 4;
  float bp = 0.f;
  for (int w = ch*16; w < ch*16+16; ++w) bp += ws[O_HW + l*W_ + w]*w_scen[s*W_+w];
  bp = redchunk(bp);
  if (lane < 16) ws[O_BWS + l*S + s] = bp;
}

__global__ void k_scal(const float* Pd, const float* w_exp, const float* w_scen, float* ws){
  __shared__ float sr[256];
  int tid = threadIdx.x;
  float p = 0.f;
  for (int i = tid; i < NN; i += 256) p += Pd[i];
  for (int i = tid; i < W_; i += 256) p -= w_exp[i];
  sr[tid] = p; __syncthreads();
  for (int o = 128; o > 0; o >>= 1){ if (tid < o) sr[tid] += sr[tid+o]; __syncthreads(); }
  if (tid == 0) ws[O_BE1] = sr[0];
  if (tid < S){
    float a = 0.f;
    for (int w = 0; w < W_; ++w) a += w_scen[tid*W_+w];
    ws[O_BE2+tid] = -a;
  }
}

// ---------------- persistent solver ----------------
extern "C" __global__ void __launch_bounds__(TPB)
k_solver(float* __restrict__ ws, const float* __restrict__ Pmax,
         const float* __restrict__ Cost, const float* __restrict__ Crup,
         const float* __restrict__ Crdn, const float* __restrict__ PTDF,
         const float* __restrict__ Cap, float* __restrict__ out)
{
  const int tid  = threadIdx.x;
  const int lane = tid & 63;
  const int wv   = tid >> 6;
  const int bid  = blockIdx.x;
  const int gw   = bid*8 + wv;        // 0..255
  const int gtid = bid*TPB + tid;
  const int s = lane & 15, ch = lane >> 4;
  unsigned nbar = 0;
  __shared__ __align__(16) float lds[L_TOT];

#ifdef HAVE_BLD4
  auto wrs = __builtin_amdgcn_make_buffer_rsrc((void*)ws, (short)0, -1, 0x00020000);
  auto LDC4 = [&](int eoff)->fx4{
    return __builtin_bit_cast(fx4,
      __builtin_amdgcn_raw_ptr_buffer_load_b128(wrs, eoff*4, 0, 17));
  };
#else
  auto LDC4 = [&](int eoff)->fx4{
    float2 a = ald2(ws+eoff), b = ald2(ws+eoff+2);
    fx4 v; v.x=a.x; v.y=a.y; v.z=b.x; v.w=b.y; return v;
  };
#endif

  const bool isU = (gw < 80);          // waves 0..79: u-work (u = 2gw, 2gw+1), WGs 0..9
  const int nbase = gw - 80;           // waves 80..255: n = nbase + 176*r

  // persistent register state
  float xp[2],xru[2],xrd[2],xpu[2],xpd[2];
  float ry1[2],ry2[2],ry5[2],ry6[2];
  float xsu[3],xsd[3];
  float ly3[2],ly4[2],ly7[2],ly8[2];
  float rz1=0.f, rz2=0.f;
  float tau=0.f, sig=0.f;
#pragma unroll
  for (int r=0;r<2;++r){ xp[r]=xru[r]=xrd[r]=xpu[r]=xpd[r]=1.f;
                         ry1[r]=ry2[r]=ry5[r]=ry6[r]=0.f;
                         ly3[r]=ly4[r]=ly7[r]=ly8[r]=0.f; }
#pragma unroll
  for (int r=0;r<3;++r){ xsu[r]=xsd[r]=1.f; }

  // ---- fence-free all-to-all grid barrier (32 flags, padded) ----
  unsigned* arr = (unsigned*)(ws + O_ARR);
  auto gbar = [&](){
    ++nbar;
    __syncthreads();                  // drains vmcnt -> all agent stores acked at MALL
    if (tid < WGN){
      if (tid == bid) astu(&arr[bid*16], nbar);
      while (aldu(&arr[tid*16]) < nbar) {}
    }
    __syncthreads();
  };

  // ---- phase Y: per-line A-apply (power) / dual update (pdhg) ----
  auto phaseY = [&](bool pd, int k){
    float scl = 1.f;
    if (!pd && k > 0) scl = 1.f/sqrtf(ald(ws+O_N2+k));
    // stage XBP, SDIFF, DIFF into LDS (coherent 16B loads)
    for (int i = tid; i < 40; i += TPB){ ((fx4*)(lds+L_XP))[i] = LDC4(O_XBP+4*i); }
    for (int i = tid; i < 100; i += TPB){ ((fx4*)(lds+L_SD))[i] = LDC4(O_SDIFF+4*i); }
    for (int i = tid; i < 640; i += TPB){
      fx4 v = LDC4(O_DIFF+4*i);
      int e = 4*i, uu = e >> 4, s0 = e & 15;
      float* d = lds + L_DF + uu*17 + s0;
      d[0]=v.x; d[1]=v.y; d[2]=v.z; d[3]=v.w;
    }
    if (pd && bid == 0){
      for (int i = tid; i < 160; i += TPB){ ((fx4*)(lds+L_P))[i] = LDC4(O_PART+4*i); }
    }
    __syncthreads();

    // WG0 wave7: z-update from PART partials (pdhg only)
    if (pd && bid == 0 && wv == 7){
      float acc = 0.f;
      if (lane < 18){
        for (int i = 0; i < WGN; ++i) acc += lds[L_P + i*20 + lane];
      }
      float susd = __shfl(acc, 17, 64);
      float ae1  = __shfl(acc, 16, 64);
      if (lane < 16){
        rz2 += sig*((acc + susd) - ws[O_BE2+lane]);
        ast(ws+O_Z+2+lane, rz2);
      }
      float zst = red16((lane < 16) ? rz2 : 0.f);
      if (lane == 0) ast(ws+O_Z+1, zst);
      if (lane == 16){ rz1 += sig*(ae1 - ws[O_BE1]); ast(ws+O_Z+0, rz1); }
    }

    // per-line work: 2 lines per wave
#pragma unroll
    for (int j = 0; j < 2; ++j){
      const int l = 2*gw + j;
      const float* hg = ws + O_HG + l*U;       // L2-cached read-only
      float a = hg[lane]*lds[L_XP+lane] + hg[lane+64]*lds[L_XP+lane+64];
      if (lane < 32) a += hg[lane+128]*lds[L_XP+lane+128];
      float fp = wred64(a);
      const float4* pr  = (const float4*)(PTDF + l*NN);
      const float4* sd4 = (const float4*)(lds + L_SD);
      float b = dot4(pr[lane], sd4[lane]);
      if (lane < 36) b += dot4(pr[lane+64], sd4[lane+64]);
      float pn = wred64(b);
      const float* hgc = hg + ch*40;
      const float* dfc = lds + L_DF + (ch*40)*17 + s;
      float sc = 0.f;
#pragma unroll 8
      for (int i = 0; i < 40; ++i) sc += hgc[i]*dfc[i*17];
      sc = redchunk(sc);
      float scen = sc + fp + pn;
      float b3l = ws[O_B3+l], b4l = ws[O_B4+l];
      float sv;
      if (pd){
        float bw = ws[O_BWS + l*16 + s];
        ly7[j] = fmaxf(ly7[j] + sig*( scen - (b3l - bw)), 0.f);
        ly8[j] = fmaxf(ly8[j] + sig*(-scen - (b4l + bw)), 0.f);
        sv = ly7[j] - ly8[j];
        ly3[j] = fmaxf(ly3[j] + sig*( fp - b3l), 0.f);
        ly4[j] = fmaxf(ly4[j] + sig*(-fp - b4l), 0.f);
      } else {
        sv = 2.f*scen*scl;
        ly3[j] = fp*scl; ly4[j] = -fp*scl;
      }
      if (lane < 16) ast(ws+O_S78 + l*16 + s, sv);
      float ssum = red16(sv);
      if (lane == 0) ast2(ws+O_SW + 2*l, make_float2(ly3[j]-ly4[j]+ssum, ssum));
    }
  };

  // ---- phase X: AT-apply + primal update (+local dual state) ----
  auto phaseX = [&](bool pd, int k, bool last){
    if (tid < 20) lds[L_SACC+tid] = 0.f;
    if (bid < 10){
      // u-WGs: stage S78 transposed + W34
      for (int i = tid; i < 2048; i += TPB){
        fx4 v = LDC4(O_S78+4*i);
        int e = 4*i, ll = e >> 4, s0 = e & 15;
        lds[D_S78T + (s0  )*516 + ll] = v.x;
        lds[D_S78T + (s0+1)*516 + ll] = v.y;
        lds[D_S78T + (s0+2)*516 + ll] = v.z;
        lds[D_S78T + (s0+3)*516 + ll] = v.w;
      }
      for (int i = tid; i < 256; i += TPB){
        fx4 v = LDC4(O_SW+4*i);
        lds[D_W34+2*i] = v.x; lds[D_W34+2*i+1] = v.z;
      }
    } else {
      // n-WGs: stage S78S only
      for (int i = tid; i < 256; i += TPB){
        fx4 v = LDC4(O_SW+4*i);
        lds[D_S78S+2*i] = v.y; lds[D_S78S+2*i+1] = v.w;
      }
    }
    float scl = 1.f, z1v, z2v, zsv;
    if (pd){
      z1v = ald(ws+O_Z+0); z2v = ald(ws+O_Z+2+s); zsv = ald(ws+O_Z+1);
    } else {
      if (k > 0) scl = 1.f/sqrtf(ald(ws+O_N2+k));
      z1v = ald(ws+O_EQ1+k)*scl;
      z2v = (ald(ws+O_EQ2+k*16+s) + ald(ws+O_EQS+k))*scl;
      zsv = red16(z2v);
    }
    __syncthreads();

    float n2p=0.f, e1p=0.f, a2p=0.f, susdp=0.f, dap=0.f;
    if (isU){
#pragma unroll
      for (int r = 0; r < 2; ++r){
        int u = 2*gw + r;
        float y1,y2,y5,y6;
        if (pd){ y1=ry1[r]; y2=ry2[r]; y5=ry5[r]; y6=ry6[r]; }
        else {
          y1=(xp[r]+xru[r])*scl; y2=(xrd[r]-xp[r])*scl;
          y5=(xpu[r]-xru[r])*scl; y6=(xpd[r]-xrd[r])*scl;
        }
        const float* HT = ws + O_HGT + u*LN;   // L2-cached
        const float4* ht4 = (const float4*)HT;
        const float4* w4  = (const float4*)(lds + D_W34);
        float g = dot4(ht4[lane], w4[lane]) + dot4(ht4[lane+64], w4[lane+64]);
        float gdot = wred64(g);
        const float4* hc4 = (const float4*)(HT + ch*128);
        const float4* sc4 = (const float4*)(lds + D_S78T + s*516 + ch*128);
        float h = 0.f;
#pragma unroll 8
        for (int i = 0; i < 32; ++i) h += dot4(hc4[i], sc4[i]);
        h = redchunk(h);
        float t5 = red16(y5), t6 = red16(y6);
        float gpu = y5 + h + z2v;
        float gpd = y6 - h - z2v;
        float gp  = y1 - y2 + gdot + z1v;
        float gru = y1 - t5;
        float grd = y2 - t6;
        if (pd){
          float xo;
          xo=xp[r];  xp[r] =fmaxf(xo-tau*(Cost[u]+gp ),0.f); float xbp_=2.f*xp[r] -xo;
          xo=xru[r]; xru[r]=fmaxf(xo-tau*(Crup[u]+gru),0.f); float xbru=2.f*xru[r]-xo;
          xo=xrd[r]; xrd[r]=fmaxf(xo-tau*(Crdn[u]+grd),0.f); float xbrd=2.f*xrd[r]-xo;
          xo=xpu[r]; xpu[r]=fmaxf(xo-tau*gpu,0.f);           float xbpu=2.f*xpu[r]-xo;
          xo=xpd[r]; xpd[r]=fmaxf(xo-tau*gpd,0.f);           float xbpd=2.f*xpd[r]-xo;
          float d = xbpu - xbpd;
          if (lane == 0){ ast(ws+O_XBP+u, xbp_); e1p += xbp_; }
          if (lane < 16){ ast(ws+O_DIFF+u*16+s, d); a2p += d; }
          ry1[r]=fmaxf(y1+sig*(xbp_+xbru-Pmax[u]),0.f);
          ry2[r]=fmaxf(y2+sig*(xbrd-xbp_),0.f);
          ry5[r]=fmaxf(y5+sig*(xbpu-xbru),0.f);
          ry6[r]=fmaxf(y6+sig*(xbpd-xbrd),0.f);
          if (last){
            if (lane == 0){
              ast(ws+O_XFIN+u, xp[r]);
              dap += Cost[u]*xp[r] + Crup[u]*xru[r] + Crdn[u]*xrd[r];
              out[u]=xp[r]; out[U+u]=xru[r]; out[2*U+u]=xrd[r];
            }
            if (lane < 16){
              out[3*U + u*16 + s] = xpu[r];
              out[3*U + U*S + u*16 + s] = xpd[r];
            }
          }
        } else {
          xp[r]=gp; xru[r]=gru; xrd[r]=grd; xpu[r]=gpu; xpd[r]=gpd;
          float d = gpu - gpd;
          if (lane == 0){ ast(ws+O_XBP+u, gp); e1p += gp; n2p += gp*gp+gru*gru+grd*grd; }
          if (lane < 16){ ast(ws+O_DIFF+u*16+s, d); a2p += d; n2p += gpu*gpu+gpd*gpd; }
        }
      }
    } else {
      const float4* ss4 = (const float4*)(lds + D_S78S);
#pragma unroll
      for (int r = 0; r < 3; ++r){
        int n = nbase + 176*r;
        if (n >= NN) break;
        const float* PT = ws + O_PTDFT + n*LN;  // L2-cached
        const float4* pt4 = (const float4*)PT;
        float g = dot4(pt4[lane], ss4[lane]) + dot4(pt4[lane+64], ss4[lane+64]);
        float pt = wred64(g);
        if (pd){
          float g1 = C_VIOL + pt + zsv, g2 = C_VIOL - pt - zsv;
          float xo = xsu[r]; xsu[r] = fmaxf(xo - tau*g1, 0.f); float xb1 = 2.f*xsu[r]-xo;
          xo = xsd[r];       xsd[r] = fmaxf(xo - tau*g2, 0.f); float xb2 = 2.f*xsd[r]-xo;
          if (lane == 0){
            ast(ws+O_SDIFF+n, xb1-xb2); susdp += xb1-xb2;
            if (last) dap += C_VIOL*(xsu[r] + xsd[r]);
          }
        } else {
          float gsu = pt + zsv;
          xsu[r] = gsu; xsd[r] = -gsu;
          if (lane == 0){ ast(ws+O_SDIFF+n, 2.f*gsu); susdp += 2.f*gsu; n2p += 2.f*gsu*gsu; }
        }
      }
    }
    float r1 = wred64(e1p);
    float r2 = wred64(susdp);
    float r3 = wred64(n2p + dap);
    if (lane == 0){
      atomicAdd(&lds[L_SACC+16], r1);
      atomicAdd(&lds[L_SACC+17], r2);
      atomicAdd(&lds[L_SACC+18], r3);
    }
    if (lane < 16) atomicAdd(&lds[L_SACC+s], a2p);
    __syncthreads();
    if (pd){
      if (tid < 10)
        ast2(ws+O_PART+bid*20+2*tid, make_float2(lds[L_SACC+2*tid], lds[L_SACC+2*tid+1]));
    } else {
      if (tid < 16) atomicAdd(&ws[O_EQ2+(k+1)*16+tid], lds[L_SACC+tid]);
      else if (tid == 16) atomicAdd(&ws[O_EQ1+k+1], lds[L_SACC+16]);
      else if (tid == 17) atomicAdd(&ws[O_EQS+k+1], lds[L_SACC+17]);
      else if (tid == 18) atomicAdd(&ws[O_N2 +k+1], lds[L_SACC+18]);
    }
  };

  // ---- power iteration ----
  for (int kk = 0; kk <= N_POWER; ++kk){
    phaseY(false, kk); gbar();
    phaseX(false, kk, false); gbar();
  }

  // ---- step sizes ----
  {
    float Lop = sqrtf(sqrtf(ald(ws+O_N2+31)));
    tau = 0.9f/Lop; sig = 0.9f/Lop;
  }

  // ---- transition: zero register + exchange state ----
#pragma unroll
  for (int r=0;r<2;++r){ xp[r]=xru[r]=xrd[r]=xpu[r]=xpd[r]=0.f;
                         ry1[r]=ry2[r]=ry5[r]=ry6[r]=0.f;
                         ly3[r]=ly4[r]=ly7[r]=ly8[r]=0.f; }
#pragma unroll
  for (int r=0;r<3;++r){ xsu[r]=xsd[r]=0.f; }
  rz1 = rz2 = 0.f;
  for (int i = gtid; i < O_ZEND - O_S78; i += NTH) ast(ws+O_S78+i, 0.f);
  gbar();

  // ---- PDHG ----
  for (int it = 0; it < N_ITERS; ++it){
    phaseX(true, it, it == N_ITERS-1); gbar();
    if (it < N_ITERS-1){ phaseY(true, it); gbar(); }
  }

  // ---- epilogue: flows + DA cost ----
  for (int i = tid; i < 40; i += TPB){ ((fx4*)(lds+L_XP))[i] = LDC4(O_XFIN+4*i); }
  __syncthreads();
#pragma unroll
  for (int j = 0; j < 2; ++j){
    const int l = 2*gw + j;
    const float* hg = ws + O_HG + l*U;
    float a = hg[lane]*lds[L_XP+lane] + hg[lane+64]*lds[L_XP+lane+64];
    if (lane < 32) a += hg[lane+128]*lds[L_XP+lane+128];
    float flow = wred64(a) + ws[O_CF+l];
    if (lane == 0){
      out[3*U + 2*U*S + l]      = Cap[l] - flow;
      out[3*U + 2*U*S + LN + l] = Cap[l] + flow;
    }
  }
  if (bid == 0 && wv == 0){
    float da = (lane < WGN) ? ald(ws+O_PART+lane*20+18) : 0.f;
    da = wred64(da);
    if (lane == 0) out[3*U + 2*U*S + 2*LN] = da;
  }
}

// ---------------- host entry ----------------
extern "C" void kernel_launch(void* const* d_in, const int* in_sizes, int n_in,
                              void* d_out, int out_size, void* d_ws, size_t ws_size,
                              hipStream_t stream){
  const float* w_scen = (const float*)d_in[0];
  const float* Pmax   = (const float*)d_in[1];
  const float* Cost   = (const float*)d_in[2];
  const float* Crup   = (const float*)d_in[3];
  const float* Crdn   = (const float*)d_in[4];
  const float* PTDF   = (const float*)d_in[5];
  const float* nG     = (const float*)d_in[6];
  const float* nW     = (const float*)d_in[7];
  const float* nL     = (const float*)d_in[8];
  const float* Pd     = (const float*)d_in[9];
  const float* w_exp  = (const float*)d_in[10];
  const float* Cap    = (const float*)d_in[11];
  float* ws  = (float*)d_ws;
  float* out = (float*)d_out;

  k_zero<<<dim3(64),  dim3(256), 0, stream>>>(ws);
  k_pdl <<<dim3(NN),  dim3(64),  0, stream>>>(nL, Pd, ws);
  k_hg  <<<dim3(LN),  dim3(U),   0, stream>>>(PTDF, nG, ws);
  k_hw  <<<dim3(LN),  dim3(W_),  0, stream>>>(PTDF, nW, ws);
  k_tp  <<<dim3(NN),  dim3(256), 0, stream>>>(PTDF, ws);
  k_misc<<<dim3(LN),  dim3(64),  0, stream>>>(PTDF, w_exp, w_scen, Cap, ws);
  k_scal<<<dim3(1),   dim3(256), 0, stream>>>(Pd, w_exp, w_scen, ws);
  k_solver<<<dim3(WGN), dim3(TPB), 0, stream>>>(ws, Pmax, Cost, Crup, Crdn, PTDF, Cap, out);
}